// Round 2
// baseline (763.387 us; speedup 1.0000x reference)
//
#include <hip/hip_runtime.h>
#include <hip/hip_bf16.h>
#include <float.h>

#define N_NODES  50000
#define N_EDGES  640000
#define N_GRAPHS 128
#define DIM      128

__global__ void zero_i32(int* p, int n){
  int i = blockIdx.x*blockDim.x + threadIdx.x;
  if (i < n) p[i] = 0;
}

__global__ void count_in(const int* __restrict__ col, int* __restrict__ cnt){
  int e = blockIdx.x*blockDim.x + threadIdx.x;
  if (e < N_EDGES) atomicAdd(&cnt[col[e]], 1);
}

__global__ void make_dis(const int* __restrict__ cnt, float* __restrict__ dis){
  int i = blockIdx.x*blockDim.x + threadIdx.x;
  if (i < N_NODES) dis[i] = 1.0f / sqrtf((float)(cnt[i] + 1)); // +1 self-loop
}

// single-workgroup exclusive scan over n ints (n ~ 50000)
__global__ void scan_excl(const int* __restrict__ cnt, int* __restrict__ offs, int n){
  __shared__ int buf[1024];
  __shared__ int carry;
  int tid = threadIdx.x;
  if (tid == 0) carry = 0;
  __syncthreads();
  for (int base = 0; base < n; base += 1024){
    int i = base + tid;
    int v = (i < n) ? cnt[i] : 0;
    buf[tid] = v; __syncthreads();
    for (int s = 1; s < 1024; s <<= 1){
      int t = (tid >= s) ? buf[tid - s] : 0;
      __syncthreads();
      buf[tid] += t;
      __syncthreads();
    }
    if (i < n) offs[i] = carry + buf[tid] - v;
    __syncthreads();
    if (tid == 0) carry += buf[1023];
    __syncthreads();
  }
  if (tid == 0) offs[n] = carry;
}

__global__ void fill_csr(const int* __restrict__ ei, const float* __restrict__ dis,
                         const int* __restrict__ offs, int* __restrict__ cursor,
                         int* __restrict__ src, float* __restrict__ wn){
  int e = blockIdx.x*blockDim.x + threadIdx.x;
  if (e >= N_EDGES) return;
  int r = ei[e];
  int c = ei[N_EDGES + e];
  int pos = offs[c] + atomicAdd(&cursor[c], 1);
  src[pos] = r;
  wn[pos]  = dis[r] * dis[c];
}

__global__ void graph_starts(const int* __restrict__ batch, int* __restrict__ gs){
  int i = blockIdx.x*blockDim.x + threadIdx.x;
  if (i >= N_NODES) return;
  int b  = batch[i];
  int bp = (i == 0) ? -1 : batch[i-1];
  for (int g = bp + 1; g <= b; ++g) gs[g] = i;
  if (i == N_NODES - 1)
    for (int g = b + 1; g <= N_GRAPHS; ++g) gs[g] = N_NODES;
}

// C[i][o] = sum_k A[i][k]*W[o][k] + bias[o]   (A:[N,128], W:[128,128])
__global__ __launch_bounds__(256) void gemm_xw(const float* __restrict__ A,
    const float* __restrict__ W, const float* __restrict__ bias,
    float* __restrict__ C){
  __shared__ float wl[128*129];   // stride 129 -> bank (col+k)&31, conflict-free
  __shared__ float al[8][128];
  int tid = threadIdx.x;
  for (int idx = tid; idx < 128*128; idx += 256)
    wl[(idx >> 7)*129 + (idx & 127)] = W[idx];
  int col = tid & 127;
  int rg  = tid >> 7;   // 0..1
  float b = bias[col];
  __syncthreads();
  const int ntiles = N_NODES/8;   // 6250
  for (int tile = blockIdx.x; tile < ntiles; tile += gridDim.x){
    int row0 = tile*8;
    for (int idx = tid; idx < 1024; idx += 256)
      al[idx >> 7][idx & 127] = A[row0*128 + idx];
    __syncthreads();
    float a0=0.f, a1=0.f, a2=0.f, a3=0.f;
    #pragma unroll 8
    for (int k = 0; k < 128; ++k){
      float w = wl[col*129 + k];
      a0 += al[rg  ][k]*w;
      a1 += al[rg+2][k]*w;
      a2 += al[rg+4][k]*w;
      a3 += al[rg+6][k]*w;
    }
    float* Cr = C + row0*128 + col;
    Cr[(rg  )*128] = a0 + b;
    Cr[(rg+2)*128] = a1 + b;
    Cr[(rg+4)*128] = a2 + b;
    Cr[(rg+6)*128] = a3 + b;
    __syncthreads();
  }
}

// one wave per node: xout[c] = dis[c]^2*xw[c] + sum_in wn*xw[src]
__global__ __launch_bounds__(256) void aggregate(const float* __restrict__ xw,
    const int* __restrict__ offs, const int* __restrict__ src,
    const float* __restrict__ wn, const float* __restrict__ dis,
    float* __restrict__ xout){
  int node = blockIdx.x*4 + (threadIdx.x >> 6);
  if (node >= N_NODES) return;
  int lane = threadIdx.x & 63;
  const float2* xw2 = (const float2*)xw;
  float d = dis[node];
  float2 v = xw2[node*64 + lane];
  float accx = d*d*v.x, accy = d*d*v.y;
  int s0 = offs[node], s1 = offs[node+1];
  for (int e = s0; e < s1; ++e){
    int r   = src[e];
    float w = wn[e];
    float2 u = xw2[r*64 + lane];
    accx += w*u.x;
    accy += w*u.y;
  }
  ((float2*)xout)[node*64 + lane] = make_float2(accx, accy);
}

// in-place relu + gate[i] = dot(x[i], gw) + gb
__global__ __launch_bounds__(256) void relu_gate(float* __restrict__ x,
    const float* __restrict__ gw, const float* __restrict__ gb,
    float* __restrict__ gate){
  int node = blockIdx.x*4 + (threadIdx.x >> 6);
  if (node >= N_NODES) return;
  int lane = threadIdx.x & 63;
  float2* x2 = (float2*)x;
  float2 v = x2[node*64 + lane];
  v.x = fmaxf(v.x, 0.f);
  v.y = fmaxf(v.y, 0.f);
  x2[node*64 + lane] = v;
  const float2* g2 = (const float2*)gw;
  float2 g = g2[lane];
  float p = v.x*g.x + v.y*g.y;
  #pragma unroll
  for (int o = 32; o > 0; o >>= 1) p += __shfl_xor(p, o, 64);
  if (lane == 0) gate[node] = p + gb[0];
}

// one block per graph: softmax-weighted pooling, accumulate into hg
__global__ __launch_bounds__(256) void att_pool(const float* __restrict__ x,
    float* __restrict__ gate, const int* __restrict__ gs,
    float* __restrict__ hg, int first){
  int g = blockIdx.x, tid = threadIdx.x;
  int s = gs[g], e = gs[g+1];
  __shared__ float red[256];
  // pass 1: max gate
  float m = -FLT_MAX;
  for (int i = s + tid; i < e; i += 256) m = fmaxf(m, gate[i]);
  red[tid] = m; __syncthreads();
  for (int st = 128; st > 0; st >>= 1){
    if (tid < st) red[tid] = fmaxf(red[tid], red[tid+st]);
    __syncthreads();
  }
  m = red[0]; __syncthreads();
  // pass 2: e = exp(gate-m) (cached in gate), sum
  float p = 0.f;
  for (int i = s + tid; i < e; i += 256){
    float ev = __expf(gate[i] - m);
    gate[i] = ev;
    p += ev;
  }
  red[tid] = p; __syncthreads();
  for (int st = 128; st > 0; st >>= 1){
    if (tid < st) red[tid] += red[tid+st];
    __syncthreads();
  }
  float ssum = red[0]; __syncthreads();
  // pass 3: weighted feature sum
  int dim = tid & 127, half = tid >> 7;
  float acc = 0.f;
  for (int i = s + half; i < e; i += 2)
    acc += gate[i] * x[i*128 + dim];
  red[tid] = acc; __syncthreads();
  if (tid < 128){
    float tot = red[tid] + red[tid+128];
    float val = (ssum > 0.f) ? tot/ssum : 0.f;
    if (first) hg[g*128 + tid] = val;
    else       hg[g*128 + tid] += val;
  }
}

// out[g] = relu(hg[g] @ lin_w.T + lin_b) @ cls_w.T + cls_b
__global__ __launch_bounds__(256) void head(const float* __restrict__ hg,
    const float* __restrict__ lw, const float* __restrict__ lb,
    const float* __restrict__ cw, const float* __restrict__ cb,
    float* __restrict__ out){
  int g = blockIdx.x, tid = threadIdx.x;
  __shared__ float h[128];
  __shared__ float t1[256];
  __shared__ float red[256];
  if (tid < 128) h[tid] = hg[g*128 + tid];
  __syncthreads();
  const float* wr = lw + tid*128;
  float a = 0.f;
  for (int k = 0; k < 128; ++k) a += h[k]*wr[k];
  a = fmaxf(a + lb[tid], 0.f);
  t1[tid] = a;
  __syncthreads();
  int o = tid >> 7, j = tid & 127;
  float p = t1[j]*cw[o*256 + j] + t1[j+128]*cw[o*256 + j + 128];
  red[tid] = p; __syncthreads();
  for (int st = 64; st > 0; st >>= 1){
    if (j < st) red[tid] += red[tid+st];
    __syncthreads();
  }
  if (j == 0) out[g*2 + o] = red[tid] + cb[o];
}

extern "C" void kernel_launch(void* const* d_in, const int* in_sizes, int n_in,
                              void* d_out, int out_size, void* d_ws, size_t ws_size,
                              hipStream_t stream){
  const float* x   = (const float*)d_in[0];
  const int*   ei  = (const int*)d_in[1];
  const int* batch = (const int*)d_in[2];
  const float* w0  = (const float*)d_in[3];
  const float* b0  = (const float*)d_in[4];
  const float* w1  = (const float*)d_in[5];
  const float* b1  = (const float*)d_in[6];
  const float* w2  = (const float*)d_in[7];
  const float* b2  = (const float*)d_in[8];
  const float* gw  = (const float*)d_in[9];
  const float* gb  = (const float*)d_in[10];
  const float* lw  = (const float*)d_in[11];
  const float* lb  = (const float*)d_in[12];
  const float* cw  = (const float*)d_in[13];
  const float* cb  = (const float*)d_in[14];
  float* out = (float*)d_out;
  (void)in_sizes; (void)n_in; (void)out_size; (void)ws_size;

  char* ws = (char*)d_ws;
  size_t off = 0;
  auto alloc = [&](size_t bytes)->char*{
    char* p = ws + off;
    off = (off + bytes + 255) & ~(size_t)255;
    return p;
  };
  float* dis   = (float*)alloc((size_t)N_NODES*4);
  float* xw    = (float*)alloc((size_t)N_NODES*DIM*4);
  float* xbuf  = (float*)alloc((size_t)N_NODES*DIM*4);
  float* gate  = (float*)alloc((size_t)N_NODES*4);
  float* hg    = (float*)alloc((size_t)N_GRAPHS*DIM*4);
  int*   gs    = (int*)alloc((size_t)(N_GRAPHS+1)*4);
  int*   cnt   = (int*)alloc((size_t)N_NODES*4);
  int*   cursor= (int*)alloc((size_t)N_NODES*4);
  int*   offs  = (int*)alloc((size_t)(N_NODES+1)*4);
  int*   srcb  = (int*)alloc((size_t)N_EDGES*4);
  float* wn    = (float*)alloc((size_t)N_EDGES*4);

  const int T = 256;
  zero_i32<<<(N_NODES+T-1)/T, T, 0, stream>>>(cnt,    N_NODES);
  zero_i32<<<(N_NODES+T-1)/T, T, 0, stream>>>(cursor, N_NODES);
  count_in<<<(N_EDGES+T-1)/T, T, 0, stream>>>(ei + N_EDGES, cnt);
  make_dis<<<(N_NODES+T-1)/T, T, 0, stream>>>(cnt, dis);
  scan_excl<<<1, 1024, 0, stream>>>(cnt, offs, N_NODES);
  fill_csr<<<(N_EDGES+T-1)/T, T, 0, stream>>>(ei, dis, offs, cursor, srcb, wn);
  graph_starts<<<(N_NODES+T-1)/T, T, 0, stream>>>(batch, gs);

  const float* xin = x;
  const float* Ws[3] = {w0, w1, w2};
  const float* Bs[3] = {b0, b1, b2};
  for (int L = 0; L < 3; ++L){
    gemm_xw  <<<512, 256, 0, stream>>>(xin, Ws[L], Bs[L], xw);
    aggregate<<<N_NODES/4, 256, 0, stream>>>(xw, offs, srcb, wn, dis, xbuf);
    relu_gate<<<N_NODES/4, 256, 0, stream>>>(xbuf, gw, gb, gate);
    att_pool <<<N_GRAPHS, 256, 0, stream>>>(xbuf, gate, gs, hg, (L==0) ? 1 : 0);
    xin = xbuf;
  }
  head<<<N_GRAPHS, 256, 0, stream>>>(hg, lw, lb, cw, cb, out);
}

// Round 3
// 682.548 us; speedup vs baseline: 1.1184x; 1.1184x over previous
//
#include <hip/hip_runtime.h>
#include <hip/hip_bf16.h>
#include <float.h>

#define N_NODES  50000
#define N_EDGES  640000
#define N_GRAPHS 128
#define DIM      128

__global__ void zero2_i32(int* a, int* b, int n){
  int i = blockIdx.x*blockDim.x + threadIdx.x;
  if (i < n){ a[i] = 0; b[i] = 0; }
}

__global__ void count_in(const int* __restrict__ col, int* __restrict__ cnt){
  int e = blockIdx.x*blockDim.x + threadIdx.x;
  if (e < N_EDGES) atomicAdd(&cnt[col[e]], 1);
}

__global__ void make_dis(const int* __restrict__ cnt, float* __restrict__ dis){
  int i = blockIdx.x*blockDim.x + threadIdx.x;
  if (i < N_NODES) dis[i] = 1.0f / sqrtf((float)(cnt[i] + 1)); // +1 self-loop
}

// single-block exclusive scan: 1024 threads x 49 contiguous elements each.
// wave shfl scan (no barriers) + 16-wave LDS scan: 2 barriers total.
__global__ __launch_bounds__(1024) void scan_excl(const int* __restrict__ cnt,
                                                  int* __restrict__ offs, int n){
  const int S = 49;                 // 1024*49 = 50176 >= n+1
  __shared__ int wsum[16];
  int tid  = threadIdx.x;
  int lane = tid & 63, w = tid >> 6;
  int base = tid * S;
  int loc = 0;
  for (int j = 0; j < S; ++j){
    int i = base + j;
    if (i < n) loc += cnt[i];
  }
  int p = loc;
  #pragma unroll
  for (int s = 1; s < 64; s <<= 1){
    int t = __shfl_up(p, s, 64);
    if (lane >= s) p += t;
  }
  if (lane == 63) wsum[w] = p;
  __syncthreads();
  if (tid < 16){
    int q = wsum[tid];
    #pragma unroll
    for (int s = 1; s < 16; s <<= 1){
      int t = __shfl_up(q, s, 16);
      if ((tid & 15) >= s) q += t;
    }
    wsum[tid] = q;                  // inclusive scan of wave sums
  }
  __syncthreads();
  int run = p - loc + ((w > 0) ? wsum[w-1] : 0);   // exclusive prefix at base
  for (int j = 0; j < S; ++j){
    int i = base + j;
    if (i <= n){
      offs[i] = run;
      if (i < n) run += cnt[i];
    }
  }
}

__global__ void fill_csr(const int* __restrict__ ei, const float* __restrict__ dis,
                         const int* __restrict__ offs, int* __restrict__ cursor,
                         int* __restrict__ src, float* __restrict__ wn){
  int e = blockIdx.x*blockDim.x + threadIdx.x;
  if (e >= N_EDGES) return;
  int r = ei[e];
  int c = ei[N_EDGES + e];
  int pos = offs[c] + atomicAdd(&cursor[c], 1);
  src[pos] = r;
  wn[pos]  = dis[r] * dis[c];
}

__global__ void graph_starts(const int* __restrict__ batch, int* __restrict__ gs){
  int i = blockIdx.x*blockDim.x + threadIdx.x;
  if (i >= N_NODES) return;
  int b  = batch[i];
  int bp = (i == 0) ? -1 : batch[i-1];
  for (int g = bp + 1; g <= b; ++g) gs[g] = i;
  if (i == N_NODES - 1)
    for (int g = b + 1; g <= N_GRAPHS; ++g) gs[g] = N_NODES;
}

// C[i][o] = sum_k A[i][k]*W[o][k] + bias[o]   (A:[N,128], W:[128,128])
// float4 LDS reads: per 4-k chunk, 1 per-lane wl b128 + 8 broadcast al b128 -> 32 FMA
__global__ __launch_bounds__(256) void gemm_xw(const float* __restrict__ A,
    const float* __restrict__ W, const float* __restrict__ bias,
    float* __restrict__ C){
  __shared__ float wl[128*132];   // stride 132: float4-aligned, perm-class banks
  __shared__ float al[16][128];
  int tid = threadIdx.x;
  for (int idx = tid; idx < 128*128; idx += 256){
    int o = idx >> 7, k = idx & 127;
    wl[o*132 + k] = W[idx];
  }
  int col = tid & 127;
  int rg  = tid >> 7;   // 0..1 (wave-uniform)
  float b = bias[col];
  __syncthreads();
  const int ntiles = N_NODES/16;   // 3125
  for (int tile = blockIdx.x; tile < ntiles; tile += gridDim.x){
    int row0 = tile*16;
    for (int idx = tid; idx < 2048; idx += 256)
      al[idx >> 7][idx & 127] = A[row0*128 + idx];
    __syncthreads();
    float acc[8];
    #pragma unroll
    for (int i = 0; i < 8; ++i) acc[i] = b;
    const float4* wp = (const float4*)(wl + col*132);
    #pragma unroll 4
    for (int kc = 0; kc < 32; ++kc){
      float4 w4 = wp[kc];
      #pragma unroll
      for (int i = 0; i < 8; ++i){
        float4 a4 = *(const float4*)&al[2*i + rg][kc*4];  // wave-broadcast
        acc[i] += a4.x*w4.x + a4.y*w4.y + a4.z*w4.z + a4.w*w4.w;
      }
    }
    #pragma unroll
    for (int i = 0; i < 8; ++i)
      C[(row0 + 2*i + rg)*128 + col] = acc[i];
    __syncthreads();
  }
}

// one wave per node: xout[c] = relu(dis[c]^2*xw[c] + sum_in wn*xw[src]);
// fused gate[c] = dot(xout[c], gw) + gb
__global__ __launch_bounds__(256) void aggregate(const float* __restrict__ xw,
    const int* __restrict__ offs, const int* __restrict__ src,
    const float* __restrict__ wn, const float* __restrict__ dis,
    float* __restrict__ xout, const float* __restrict__ gw,
    const float* __restrict__ gb, float* __restrict__ gate){
  int node = blockIdx.x*4 + (threadIdx.x >> 6);
  if (node >= N_NODES) return;
  int lane = threadIdx.x & 63;
  const float2* xw2 = (const float2*)xw;
  float d = dis[node];
  float2 v = xw2[node*64 + lane];
  float accx = d*d*v.x, accy = d*d*v.y;
  int s0 = offs[node], s1 = offs[node+1];
  int e = s0;
  for (; e + 4 <= s1; e += 4){
    int r0 = src[e], r1 = src[e+1], r2 = src[e+2], r3 = src[e+3];
    float w0 = wn[e], w1 = wn[e+1], w2 = wn[e+2], w3 = wn[e+3];
    float2 u0 = xw2[r0*64 + lane];
    float2 u1 = xw2[r1*64 + lane];
    float2 u2 = xw2[r2*64 + lane];
    float2 u3 = xw2[r3*64 + lane];
    accx += w0*u0.x; accy += w0*u0.y;
    accx += w1*u1.x; accy += w1*u1.y;
    accx += w2*u2.x; accy += w2*u2.y;
    accx += w3*u3.x; accy += w3*u3.y;
  }
  for (; e < s1; ++e){
    int r   = src[e];
    float w = wn[e];
    float2 u = xw2[r*64 + lane];
    accx += w*u.x; accy += w*u.y;
  }
  accx = fmaxf(accx, 0.f);
  accy = fmaxf(accy, 0.f);
  ((float2*)xout)[node*64 + lane] = make_float2(accx, accy);
  float2 g = ((const float2*)gw)[lane];
  float p = accx*g.x + accy*g.y;
  #pragma unroll
  for (int o = 32; o > 0; o >>= 1) p += __shfl_xor(p, o, 64);
  if (lane == 0) gate[node] = p + gb[0];
}

// one block per graph: softmax-weighted pooling, accumulate into hg
__global__ __launch_bounds__(256) void att_pool(const float* __restrict__ x,
    float* __restrict__ gate, const int* __restrict__ gs,
    float* __restrict__ hg, int first){
  int g = blockIdx.x, tid = threadIdx.x;
  int s = gs[g], e = gs[g+1];
  __shared__ float red[256];
  float m = -FLT_MAX;
  for (int i = s + tid; i < e; i += 256) m = fmaxf(m, gate[i]);
  red[tid] = m; __syncthreads();
  for (int st = 128; st > 0; st >>= 1){
    if (tid < st) red[tid] = fmaxf(red[tid], red[tid+st]);
    __syncthreads();
  }
  m = red[0]; __syncthreads();
  float p = 0.f;
  for (int i = s + tid; i < e; i += 256){
    float ev = __expf(gate[i] - m);
    gate[i] = ev;
    p += ev;
  }
  red[tid] = p; __syncthreads();
  for (int st = 128; st > 0; st >>= 1){
    if (tid < st) red[tid] += red[tid+st];
    __syncthreads();
  }
  float ssum = red[0]; __syncthreads();
  int dim = tid & 127, half = tid >> 7;
  float acc = 0.f;
  for (int i = s + half; i < e; i += 2)
    acc += gate[i] * x[i*128 + dim];
  red[tid] = acc; __syncthreads();
  if (tid < 128){
    float tot = red[tid] + red[tid+128];
    float val = (ssum > 0.f) ? tot/ssum : 0.f;
    if (first) hg[g*128 + tid] = val;
    else       hg[g*128 + tid] += val;
  }
}

// out[g] = relu(hg[g] @ lin_w.T + lin_b) @ cls_w.T + cls_b
__global__ __launch_bounds__(256) void head(const float* __restrict__ hg,
    const float* __restrict__ lw, const float* __restrict__ lb,
    const float* __restrict__ cw, const float* __restrict__ cb,
    float* __restrict__ out){
  int g = blockIdx.x, tid = threadIdx.x;
  __shared__ float h[128];
  __shared__ float t1[256];
  __shared__ float red[256];
  if (tid < 128) h[tid] = hg[g*128 + tid];
  __syncthreads();
  const float* wr = lw + tid*128;
  float a = 0.f;
  for (int k = 0; k < 128; ++k) a += h[k]*wr[k];
  a = fmaxf(a + lb[tid], 0.f);
  t1[tid] = a;
  __syncthreads();
  int o = tid >> 7, j = tid & 127;
  float p = t1[j]*cw[o*256 + j] + t1[j+128]*cw[o*256 + j + 128];
  red[tid] = p; __syncthreads();
  for (int st = 64; st > 0; st >>= 1){
    if (j < st) red[tid] += red[tid+st];
    __syncthreads();
  }
  if (j == 0) out[g*2 + o] = red[tid] + cb[o];
}

extern "C" void kernel_launch(void* const* d_in, const int* in_sizes, int n_in,
                              void* d_out, int out_size, void* d_ws, size_t ws_size,
                              hipStream_t stream){
  const float* x   = (const float*)d_in[0];
  const int*   ei  = (const int*)d_in[1];
  const int* batch = (const int*)d_in[2];
  const float* w0  = (const float*)d_in[3];
  const float* b0  = (const float*)d_in[4];
  const float* w1  = (const float*)d_in[5];
  const float* b1  = (const float*)d_in[6];
  const float* w2  = (const float*)d_in[7];
  const float* b2  = (const float*)d_in[8];
  const float* gw  = (const float*)d_in[9];
  const float* gb  = (const float*)d_in[10];
  const float* lw  = (const float*)d_in[11];
  const float* lb  = (const float*)d_in[12];
  const float* cw  = (const float*)d_in[13];
  const float* cb  = (const float*)d_in[14];
  float* out = (float*)d_out;
  (void)in_sizes; (void)n_in; (void)out_size; (void)ws_size;

  char* ws = (char*)d_ws;
  size_t off = 0;
  auto alloc = [&](size_t bytes)->char*{
    char* p = ws + off;
    off = (off + bytes + 255) & ~(size_t)255;
    return p;
  };
  float* dis   = (float*)alloc((size_t)N_NODES*4);
  float* xw    = (float*)alloc((size_t)N_NODES*DIM*4);
  float* xbuf  = (float*)alloc((size_t)N_NODES*DIM*4);
  float* gate  = (float*)alloc((size_t)N_NODES*4);
  float* hg    = (float*)alloc((size_t)N_GRAPHS*DIM*4);
  int*   gs    = (int*)alloc((size_t)(N_GRAPHS+1)*4);
  int*   cnt   = (int*)alloc((size_t)N_NODES*4);
  int*   cursor= (int*)alloc((size_t)N_NODES*4);
  int*   offs  = (int*)alloc((size_t)(N_NODES+1)*4);
  int*   srcb  = (int*)alloc((size_t)N_EDGES*4);
  float* wn    = (float*)alloc((size_t)N_EDGES*4);

  const int T = 256;
  zero2_i32<<<(N_NODES+T-1)/T, T, 0, stream>>>(cnt, cursor, N_NODES);
  count_in<<<(N_EDGES+T-1)/T, T, 0, stream>>>(ei + N_EDGES, cnt);
  make_dis<<<(N_NODES+T-1)/T, T, 0, stream>>>(cnt, dis);
  scan_excl<<<1, 1024, 0, stream>>>(cnt, offs, N_NODES);
  fill_csr<<<(N_EDGES+T-1)/T, T, 0, stream>>>(ei, dis, offs, cursor, srcb, wn);
  graph_starts<<<(N_NODES+T-1)/T, T, 0, stream>>>(batch, gs);

  const float* xin = x;
  const float* Ws[3] = {w0, w1, w2};
  const float* Bs[3] = {b0, b1, b2};
  for (int L = 0; L < 3; ++L){
    gemm_xw  <<<512, 256, 0, stream>>>(xin, Ws[L], Bs[L], xw);
    aggregate<<<N_NODES/4, 256, 0, stream>>>(xw, offs, srcb, wn, dis, xbuf,
                                             gw, gb, gate);
    att_pool <<<N_GRAPHS, 256, 0, stream>>>(xbuf, gate, gs, hg, (L==0) ? 1 : 0);
    xin = xbuf;
  }
  head<<<N_GRAPHS, 256, 0, stream>>>(hg, lw, lb, cw, cb, out);
}

// Round 4
// 478.993 us; speedup vs baseline: 1.5937x; 1.4250x over previous
//
#include <hip/hip_runtime.h>
#include <hip/hip_bf16.h>
#include <float.h>

#define N_NODES  50000
#define N_EDGES  640000
#define N_GRAPHS 128
#define DIM      128
#define SCAN_NB  196   // ceil(50000/256)

__global__ void zero2_i32(int* a, int* b, int n){
  int i = blockIdx.x*blockDim.x + threadIdx.x;
  if (i < n){ a[i] = 0; b[i] = 0; }
}

__global__ void count_in(const int* __restrict__ col, int* __restrict__ cnt){
  int e = blockIdx.x*blockDim.x + threadIdx.x;
  if (e < N_EDGES) atomicAdd(&cnt[col[e]], 1);
}

__global__ void make_dis(const int* __restrict__ cnt, float* __restrict__ dis){
  int i = blockIdx.x*blockDim.x + threadIdx.x;
  if (i < N_NODES) dis[i] = 1.0f / sqrtf((float)(cnt[i] + 1)); // +1 self-loop
}

// --- multi-block exclusive scan: partials -> mid scan -> finalize ---
__global__ __launch_bounds__(256) void scan_part(const int* __restrict__ cnt,
                                                 int* __restrict__ bsum, int n){
  int tid = threadIdx.x;
  int i = blockIdx.x*256 + tid;
  int v = (i < n) ? cnt[i] : 0;
  #pragma unroll
  for (int s = 32; s > 0; s >>= 1) v += __shfl_xor(v, s, 64);
  __shared__ int ws[4];
  if ((tid & 63) == 0) ws[tid >> 6] = v;
  __syncthreads();
  if (tid == 0) bsum[blockIdx.x] = ws[0] + ws[1] + ws[2] + ws[3];
}

__global__ __launch_bounds__(256) void scan_mid(const int* __restrict__ bsum,
    int* __restrict__ bpre, int* __restrict__ offs, int nb, int n){
  __shared__ int buf[256];
  int tid = threadIdx.x;
  int v = (tid < nb) ? bsum[tid] : 0;
  buf[tid] = v; __syncthreads();
  for (int s = 1; s < 256; s <<= 1){
    int t = (tid >= s) ? buf[tid - s] : 0;
    __syncthreads();
    buf[tid] += t;
    __syncthreads();
  }
  if (tid < nb) bpre[tid] = buf[tid] - v;
  if (tid == 255) offs[n] = buf[255];
}

__global__ __launch_bounds__(256) void scan_fin(const int* __restrict__ cnt,
    const int* __restrict__ bpre, int* __restrict__ offs, int n){
  int tid = threadIdx.x, lane = tid & 63, w = tid >> 6;
  int i = blockIdx.x*256 + tid;
  int v = (i < n) ? cnt[i] : 0;
  int p = v;
  #pragma unroll
  for (int s = 1; s < 64; s <<= 1){
    int t = __shfl_up(p, s, 64);
    if (lane >= s) p += t;
  }
  __shared__ int ws[4];
  if (lane == 63) ws[w] = p;
  __syncthreads();
  int wbase = 0;
  for (int j = 0; j < w; ++j) wbase += ws[j];
  if (i < n) offs[i] = bpre[blockIdx.x] + wbase + p - v;
}

__global__ void fill_csr(const int* __restrict__ ei, const float* __restrict__ dis,
                         const int* __restrict__ offs, int* __restrict__ cursor,
                         int* __restrict__ src, float* __restrict__ wn){
  int e = blockIdx.x*blockDim.x + threadIdx.x;
  if (e >= N_EDGES) return;
  int r = ei[e];
  int c = ei[N_EDGES + e];
  int pos = offs[c] + atomicAdd(&cursor[c], 1);
  src[pos] = r;
  wn[pos]  = dis[r] * dis[c];
}

__global__ void graph_starts(const int* __restrict__ batch, int* __restrict__ gs){
  int i = blockIdx.x*blockDim.x + threadIdx.x;
  if (i >= N_NODES) return;
  int b  = batch[i];
  int bp = (i == 0) ? -1 : batch[i-1];
  for (int g = bp + 1; g <= b; ++g) gs[g] = i;
  if (i == N_NODES - 1)
    for (int g = b + 1; g <= N_GRAPHS; ++g) gs[g] = N_NODES;
}

// C[i][o] = sum_k A[i][k]*W[o][k] + bias[o]   (A:[N,128], W:[128,128])
__global__ __launch_bounds__(256) void gemm_xw(const float* __restrict__ A,
    const float* __restrict__ W, const float* __restrict__ bias,
    float* __restrict__ C){
  __shared__ float wl[128*132];   // stride 132: float4-aligned
  __shared__ float al[16][128];
  int tid = threadIdx.x;
  for (int idx = tid; idx < 128*128; idx += 256){
    int o = idx >> 7, k = idx & 127;
    wl[o*132 + k] = W[idx];
  }
  int col = tid & 127;
  int rg  = tid >> 7;   // 0..1
  float b = bias[col];
  __syncthreads();
  const int ntiles = N_NODES/16;   // 3125
  for (int tile = blockIdx.x; tile < ntiles; tile += gridDim.x){
    int row0 = tile*16;
    for (int idx = tid; idx < 2048; idx += 256)
      al[idx >> 7][idx & 127] = A[row0*128 + idx];
    __syncthreads();
    float acc[8];
    #pragma unroll
    for (int i = 0; i < 8; ++i) acc[i] = b;
    const float4* wp = (const float4*)(wl + col*132);
    #pragma unroll 4
    for (int kc = 0; kc < 32; ++kc){
      float4 w4 = wp[kc];
      #pragma unroll
      for (int i = 0; i < 8; ++i){
        float4 a4 = *(const float4*)&al[2*i + rg][kc*4];  // wave-broadcast
        acc[i] += a4.x*w4.x + a4.y*w4.y + a4.z*w4.z + a4.w*w4.w;
      }
    }
    #pragma unroll
    for (int i = 0; i < 8; ++i)
      C[(row0 + 2*i + rg)*128 + col] = acc[i];
    __syncthreads();
  }
}

// one wave per node: xout[c] = relu(dis[c]^2*xw[c] + sum_in wn*xw[src]);
// fused gate[c] = dot(xout[c], gw) + gb
__global__ __launch_bounds__(256) void aggregate(const float* __restrict__ xw,
    const int* __restrict__ offs, const int* __restrict__ src,
    const float* __restrict__ wn, const float* __restrict__ dis,
    float* __restrict__ xout, const float* __restrict__ gw,
    const float* __restrict__ gb, float* __restrict__ gate){
  int node = blockIdx.x*4 + (threadIdx.x >> 6);
  if (node >= N_NODES) return;
  int lane = threadIdx.x & 63;
  const float2* xw2 = (const float2*)xw;
  float d = dis[node];
  float2 v = xw2[node*64 + lane];
  float accx = d*d*v.x, accy = d*d*v.y;
  int s0 = offs[node], s1 = offs[node+1];
  int e = s0;
  for (; e + 4 <= s1; e += 4){
    int r0 = src[e], r1 = src[e+1], r2 = src[e+2], r3 = src[e+3];
    float w0 = wn[e], w1 = wn[e+1], w2 = wn[e+2], w3 = wn[e+3];
    float2 u0 = xw2[r0*64 + lane];
    float2 u1 = xw2[r1*64 + lane];
    float2 u2 = xw2[r2*64 + lane];
    float2 u3 = xw2[r3*64 + lane];
    accx += w0*u0.x; accy += w0*u0.y;
    accx += w1*u1.x; accy += w1*u1.y;
    accx += w2*u2.x; accy += w2*u2.y;
    accx += w3*u3.x; accy += w3*u3.y;
  }
  for (; e < s1; ++e){
    int r   = src[e];
    float w = wn[e];
    float2 u = xw2[r*64 + lane];
    accx += w*u.x; accy += w*u.y;
  }
  accx = fmaxf(accx, 0.f);
  accy = fmaxf(accy, 0.f);
  ((float2*)xout)[node*64 + lane] = make_float2(accx, accy);
  float2 g = ((const float2*)gw)[lane];
  float p = accx*g.x + accy*g.y;
  #pragma unroll
  for (int o = 32; o > 0; o >>= 1) p += __shfl_xor(p, o, 64);
  if (lane == 0) gate[node] = p + gb[0];
}

// one block (1024 thr) per graph: softmax-weighted pooling, accumulate into hg
__global__ __launch_bounds__(1024) void att_pool(const float* __restrict__ x,
    float* __restrict__ gate, const int* __restrict__ gs,
    float* __restrict__ hg, int first){
  int g = blockIdx.x, tid = threadIdx.x;
  int s = gs[g], e = gs[g+1];
  __shared__ float red[1024];
  float m = -FLT_MAX;
  for (int i = s + tid; i < e; i += 1024) m = fmaxf(m, gate[i]);
  red[tid] = m; __syncthreads();
  for (int st = 512; st > 0; st >>= 1){
    if (tid < st) red[tid] = fmaxf(red[tid], red[tid+st]);
    __syncthreads();
  }
  m = red[0]; __syncthreads();
  float p = 0.f;
  for (int i = s + tid; i < e; i += 1024){
    float ev = __expf(gate[i] - m);
    gate[i] = ev;
    p += ev;
  }
  red[tid] = p; __syncthreads();
  for (int st = 512; st > 0; st >>= 1){
    if (tid < st) red[tid] += red[tid+st];
    __syncthreads();
  }
  float ssum = red[0]; __syncthreads();
  int dim = tid & 127, half = tid >> 7;   // 8 row-groups
  float acc = 0.f;
  for (int i = s + half; i < e; i += 8)
    acc += gate[i] * x[i*128 + dim];
  red[tid] = acc; __syncthreads();
  for (int st = 512; st >= 128; st >>= 1){
    if (tid < st) red[tid] += red[tid+st];
    __syncthreads();
  }
  if (tid < 128){
    float val = (ssum > 0.f) ? red[tid]/ssum : 0.f;
    if (first) hg[g*128 + tid] = val;
    else       hg[g*128 + tid] += val;
  }
}

// out[g] = relu(hg[g] @ lin_w.T + lin_b) @ cls_w.T + cls_b
__global__ __launch_bounds__(256) void head(const float* __restrict__ hg,
    const float* __restrict__ lw, const float* __restrict__ lb,
    const float* __restrict__ cw, const float* __restrict__ cb,
    float* __restrict__ out){
  int g = blockIdx.x, tid = threadIdx.x;
  __shared__ float h[128];
  __shared__ float t1[256];
  __shared__ float red[256];
  if (tid < 128) h[tid] = hg[g*128 + tid];
  __syncthreads();
  const float* wr = lw + tid*128;
  float a = 0.f;
  for (int k = 0; k < 128; ++k) a += h[k]*wr[k];
  a = fmaxf(a + lb[tid], 0.f);
  t1[tid] = a;
  __syncthreads();
  int o = tid >> 7, j = tid & 127;
  float p = t1[j]*cw[o*256 + j] + t1[j+128]*cw[o*256 + j + 128];
  red[tid] = p; __syncthreads();
  for (int st = 64; st > 0; st >>= 1){
    if (j < st) red[tid] += red[tid+st];
    __syncthreads();
  }
  if (j == 0) out[g*2 + o] = red[tid] + cb[o];
}

extern "C" void kernel_launch(void* const* d_in, const int* in_sizes, int n_in,
                              void* d_out, int out_size, void* d_ws, size_t ws_size,
                              hipStream_t stream){
  const float* x   = (const float*)d_in[0];
  const int*   ei  = (const int*)d_in[1];
  const int* batch = (const int*)d_in[2];
  const float* w0  = (const float*)d_in[3];
  const float* b0  = (const float*)d_in[4];
  const float* w1  = (const float*)d_in[5];
  const float* b1  = (const float*)d_in[6];
  const float* w2  = (const float*)d_in[7];
  const float* b2  = (const float*)d_in[8];
  const float* gw  = (const float*)d_in[9];
  const float* gb  = (const float*)d_in[10];
  const float* lw  = (const float*)d_in[11];
  const float* lb  = (const float*)d_in[12];
  const float* cw  = (const float*)d_in[13];
  const float* cb  = (const float*)d_in[14];
  float* out = (float*)d_out;
  (void)in_sizes; (void)n_in; (void)out_size; (void)ws_size;

  char* ws = (char*)d_ws;
  size_t off = 0;
  auto alloc = [&](size_t bytes)->char*{
    char* p = ws + off;
    off = (off + bytes + 255) & ~(size_t)255;
    return p;
  };
  float* dis   = (float*)alloc((size_t)N_NODES*4);
  float* xw    = (float*)alloc((size_t)N_NODES*DIM*4);
  float* xbuf  = (float*)alloc((size_t)N_NODES*DIM*4);
  float* gate  = (float*)alloc((size_t)N_NODES*4);
  float* hg    = (float*)alloc((size_t)N_GRAPHS*DIM*4);
  int*   gs    = (int*)alloc((size_t)(N_GRAPHS+1)*4);
  int*   cnt   = (int*)alloc((size_t)N_NODES*4);
  int*   cursor= (int*)alloc((size_t)N_NODES*4);
  int*   offs  = (int*)alloc((size_t)(N_NODES+1)*4);
  int*   bsum  = (int*)alloc((size_t)SCAN_NB*4);
  int*   bpre  = (int*)alloc((size_t)SCAN_NB*4);
  int*   srcb  = (int*)alloc((size_t)N_EDGES*4);
  float* wn    = (float*)alloc((size_t)N_EDGES*4);

  const int T = 256;
  zero2_i32<<<(N_NODES+T-1)/T, T, 0, stream>>>(cnt, cursor, N_NODES);
  count_in<<<(N_EDGES+T-1)/T, T, 0, stream>>>(ei + N_EDGES, cnt);
  make_dis<<<(N_NODES+T-1)/T, T, 0, stream>>>(cnt, dis);
  scan_part<<<SCAN_NB, 256, 0, stream>>>(cnt, bsum, N_NODES);
  scan_mid <<<1, 256, 0, stream>>>(bsum, bpre, offs, SCAN_NB, N_NODES);
  scan_fin <<<SCAN_NB, 256, 0, stream>>>(cnt, bpre, offs, N_NODES);
  fill_csr<<<(N_EDGES+T-1)/T, T, 0, stream>>>(ei, dis, offs, cursor, srcb, wn);
  graph_starts<<<(N_NODES+T-1)/T, T, 0, stream>>>(batch, gs);

  const float* xin = x;
  const float* Ws[3] = {w0, w1, w2};
  const float* Bs[3] = {b0, b1, b2};
  for (int L = 0; L < 3; ++L){
    gemm_xw  <<<512, 256, 0, stream>>>(xin, Ws[L], Bs[L], xw);
    aggregate<<<N_NODES/4, 256, 0, stream>>>(xw, offs, srcb, wn, dis, xbuf,
                                             gw, gb, gate);
    att_pool <<<N_GRAPHS, 1024, 0, stream>>>(xbuf, gate, gs, hg, (L==0) ? 1 : 0);
    xin = xbuf;
  }
  head<<<N_GRAPHS, 256, 0, stream>>>(hg, lw, lb, cw, cb, out);
}

// Round 5
// 310.987 us; speedup vs baseline: 2.4547x; 1.5402x over previous
//
#include <hip/hip_runtime.h>
#include <hip/hip_bf16.h>
#include <float.h>

#define N_NODES  50000
#define N_EDGES  640000
#define N_GRAPHS 128
#define DIM      128
#define SCAN_NB  196   // ceil(50000/256)

typedef __attribute__((ext_vector_type(8))) short bf16x8;
typedef __attribute__((ext_vector_type(4))) float f32x4;

__device__ __forceinline__ unsigned short f2bf(float f){
  unsigned int u = __float_as_uint(f);
  u += 0x7fffu + ((u >> 16) & 1u);     // round-to-nearest-even
  return (unsigned short)(u >> 16);
}
__device__ __forceinline__ float bf2f(unsigned short h){
  return __uint_as_float(((unsigned int)h) << 16);
}
__device__ __forceinline__ float2 up2(unsigned int p){
  return make_float2(__uint_as_float(p << 16),
                     __uint_as_float(p & 0xffff0000u));
}

__global__ void zero2_i32(int* a, int* b, int n){
  int i = blockIdx.x*blockDim.x + threadIdx.x;
  if (i < n){ a[i] = 0; b[i] = 0; }
}

__global__ void count_in(const int* __restrict__ col, int* __restrict__ cnt){
  int e = blockIdx.x*blockDim.x + threadIdx.x;
  if (e < N_EDGES) atomicAdd(&cnt[col[e]], 1);
}

__global__ void make_dis(const int* __restrict__ cnt, float* __restrict__ dis){
  int i = blockIdx.x*blockDim.x + threadIdx.x;
  if (i < N_NODES) dis[i] = 1.0f / sqrtf((float)(cnt[i] + 1)); // +1 self-loop
}

// pack 2 f32 -> 1 uint of 2 bf16
__global__ void f32_to_bf16(const float* __restrict__ in,
                            unsigned int* __restrict__ out, int n2){
  int i = blockIdx.x*blockDim.x + threadIdx.x;
  if (i < n2){
    float2 v = ((const float2*)in)[i];
    out[i] = (unsigned int)f2bf(v.x) | ((unsigned int)f2bf(v.y) << 16);
  }
}

// --- multi-block exclusive scan ---
__global__ __launch_bounds__(256) void scan_part(const int* __restrict__ cnt,
                                                 int* __restrict__ bsum, int n){
  int tid = threadIdx.x;
  int i = blockIdx.x*256 + tid;
  int v = (i < n) ? cnt[i] : 0;
  #pragma unroll
  for (int s = 32; s > 0; s >>= 1) v += __shfl_xor(v, s, 64);
  __shared__ int ws[4];
  if ((tid & 63) == 0) ws[tid >> 6] = v;
  __syncthreads();
  if (tid == 0) bsum[blockIdx.x] = ws[0] + ws[1] + ws[2] + ws[3];
}

__global__ __launch_bounds__(256) void scan_mid(const int* __restrict__ bsum,
    int* __restrict__ bpre, int* __restrict__ offs, int nb, int n){
  __shared__ int buf[256];
  int tid = threadIdx.x;
  int v = (tid < nb) ? bsum[tid] : 0;
  buf[tid] = v; __syncthreads();
  for (int s = 1; s < 256; s <<= 1){
    int t = (tid >= s) ? buf[tid - s] : 0;
    __syncthreads();
    buf[tid] += t;
    __syncthreads();
  }
  if (tid < nb) bpre[tid] = buf[tid] - v;
  if (tid == 255) offs[n] = buf[255];
}

__global__ __launch_bounds__(256) void scan_fin(const int* __restrict__ cnt,
    const int* __restrict__ bpre, int* __restrict__ offs, int n){
  int tid = threadIdx.x, lane = tid & 63, w = tid >> 6;
  int i = blockIdx.x*256 + tid;
  int v = (i < n) ? cnt[i] : 0;
  int p = v;
  #pragma unroll
  for (int s = 1; s < 64; s <<= 1){
    int t = __shfl_up(p, s, 64);
    if (lane >= s) p += t;
  }
  __shared__ int ws[4];
  if (lane == 63) ws[w] = p;
  __syncthreads();
  int wbase = 0;
  for (int j = 0; j < w; ++j) wbase += ws[j];
  if (i < n) offs[i] = bpre[blockIdx.x] + wbase + p - v;
}

__global__ void fill_csr(const int* __restrict__ ei, const float* __restrict__ dis,
                         const int* __restrict__ offs, int* __restrict__ cursor,
                         int* __restrict__ src, float* __restrict__ wn){
  int e = blockIdx.x*blockDim.x + threadIdx.x;
  if (e >= N_EDGES) return;
  int r = ei[e];
  int c = ei[N_EDGES + e];
  int pos = offs[c] + atomicAdd(&cursor[c], 1);
  src[pos] = r;
  wn[pos]  = dis[r] * dis[c];
}

__global__ void graph_starts(const int* __restrict__ batch, int* __restrict__ gs){
  int i = blockIdx.x*blockDim.x + threadIdx.x;
  if (i >= N_NODES) return;
  int b  = batch[i];
  int bp = (i == 0) ? -1 : batch[i-1];
  for (int g = bp + 1; g <= b; ++g) gs[g] = i;
  if (i == N_NODES - 1)
    for (int g = b + 1; g <= N_GRAPHS; ++g) gs[g] = N_NODES;
}

// MFMA GEMM: C[i][o] = bf16( sum_k A[i][k]*W[o][k] + bias[o] )
// A: bf16 [N][128] row-major; W: bf16 [128][128] (o,k); C: bf16 [N][128].
// One wave per 16-row tile; W fragments register-resident per wave (no LDS).
__global__ __launch_bounds__(256, 2) void gemm_mfma(
    const unsigned short* __restrict__ A, const unsigned short* __restrict__ Wb,
    const float* __restrict__ bias, unsigned short* __restrict__ C,
    int total_waves){
  int tid = threadIdx.x;
  int lane = tid & 63;
  int wid = blockIdx.x*4 + (tid >> 6);
  int l15 = lane & 15, l4 = lane >> 4;     // l4 in 0..3
  // B-frag: lane holds B[k][n] = W[n][k], n=l15(+16*ob), k=ks*32+l4*8+j
  bf16x8 wf[8][4];
  #pragma unroll
  for (int ob = 0; ob < 8; ++ob)
    #pragma unroll
    for (int ks = 0; ks < 4; ++ks)
      wf[ob][ks] = *(const bf16x8*)&Wb[(ob*16 + l15)*128 + ks*32 + l4*8];
  float bv[8];
  #pragma unroll
  for (int ob = 0; ob < 8; ++ob) bv[ob] = bias[ob*16 + l15];

  for (int t = wid; t < N_NODES/16; t += total_waves){
    int row0 = t*16;
    // A-frag: lane holds A[row0+l15][ks*32 + l4*8 + j]
    bf16x8 af[4];
    #pragma unroll
    for (int ks = 0; ks < 4; ++ks)
      af[ks] = *(const bf16x8*)&A[(size_t)(row0 + l15)*128 + ks*32 + l4*8];
    f32x4 acc[8];
    #pragma unroll
    for (int ob = 0; ob < 8; ++ob) acc[ob] = (f32x4){0.f,0.f,0.f,0.f};
    #pragma unroll
    for (int ks = 0; ks < 4; ++ks)
      #pragma unroll
      for (int ob = 0; ob < 8; ++ob)
        acc[ob] = __builtin_amdgcn_mfma_f32_16x16x32_bf16(af[ks], wf[ob][ks],
                                                          acc[ob], 0, 0, 0);
    // D: row = l4*4 + r, col = ob*16 + l15
    #pragma unroll
    for (int ob = 0; ob < 8; ++ob)
      #pragma unroll
      for (int r = 0; r < 4; ++r)
        C[(size_t)(row0 + l4*4 + r)*128 + ob*16 + l15] = f2bf(acc[ob][r] + bv[ob]);
  }
}

// one wave per node, bf16 gather: xout[c]=relu(d^2*xw[c]+sum wn*xw[src]) (bf16),
// fused gate[c] = dot(xout[c], gw) + gb  (f32)
__global__ __launch_bounds__(256) void aggregate_bf(
    const unsigned int* __restrict__ xw,   // bf16x2 per uint, row = 64 uints
    const int* __restrict__ offs, const int* __restrict__ src,
    const float* __restrict__ wn, const float* __restrict__ dis,
    unsigned int* __restrict__ xout, const float* __restrict__ gw,
    const float* __restrict__ gb, float* __restrict__ gate){
  int node = blockIdx.x*4 + (threadIdx.x >> 6);
  if (node >= N_NODES) return;
  int lane = threadIdx.x & 63;
  float d = dis[node];
  float2 vf = up2(xw[node*64 + lane]);
  float accx = d*d*vf.x, accy = d*d*vf.y;
  int s0 = offs[node], s1 = offs[node+1];
  int e = s0;
  for (; e + 4 <= s1; e += 4){
    int r0 = src[e], r1 = src[e+1], r2 = src[e+2], r3 = src[e+3];
    float w0 = wn[e], w1 = wn[e+1], w2 = wn[e+2], w3 = wn[e+3];
    float2 u0 = up2(xw[r0*64 + lane]);
    float2 u1 = up2(xw[r1*64 + lane]);
    float2 u2 = up2(xw[r2*64 + lane]);
    float2 u3 = up2(xw[r3*64 + lane]);
    accx += w0*u0.x; accy += w0*u0.y;
    accx += w1*u1.x; accy += w1*u1.y;
    accx += w2*u2.x; accy += w2*u2.y;
    accx += w3*u3.x; accy += w3*u3.y;
  }
  for (; e < s1; ++e){
    float w = wn[e];
    float2 u = up2(xw[src[e]*64 + lane]);
    accx += w*u.x; accy += w*u.y;
  }
  accx = fmaxf(accx, 0.f);
  accy = fmaxf(accy, 0.f);
  xout[node*64 + lane] = (unsigned int)f2bf(accx) | ((unsigned int)f2bf(accy) << 16);
  float2 g = ((const float2*)gw)[lane];
  float p = accx*g.x + accy*g.y;
  #pragma unroll
  for (int o = 32; o > 0; o >>= 1) p += __shfl_xor(p, o, 64);
  if (lane == 0) gate[node] = p + gb[0];
}

// one block (1024 thr) per graph: softmax pooling over bf16 x, accumulate hg (f32)
__global__ __launch_bounds__(1024) void att_pool(
    const unsigned short* __restrict__ x, float* __restrict__ gate,
    const int* __restrict__ gs, float* __restrict__ hg, int first){
  int g = blockIdx.x, tid = threadIdx.x;
  int s = gs[g], e = gs[g+1];
  __shared__ float red[1024];
  float m = -FLT_MAX;
  for (int i = s + tid; i < e; i += 1024) m = fmaxf(m, gate[i]);
  red[tid] = m; __syncthreads();
  for (int st = 512; st > 0; st >>= 1){
    if (tid < st) red[tid] = fmaxf(red[tid], red[tid+st]);
    __syncthreads();
  }
  m = red[0]; __syncthreads();
  float p = 0.f;
  for (int i = s + tid; i < e; i += 1024){
    float ev = __expf(gate[i] - m);
    gate[i] = ev;
    p += ev;
  }
  red[tid] = p; __syncthreads();
  for (int st = 512; st > 0; st >>= 1){
    if (tid < st) red[tid] += red[tid+st];
    __syncthreads();
  }
  float ssum = red[0]; __syncthreads();
  int dim = tid & 127, half = tid >> 7;   // 8 row-groups
  float acc = 0.f;
  for (int i = s + half; i < e; i += 8)
    acc += gate[i] * bf2f(x[(size_t)i*128 + dim]);
  red[tid] = acc; __syncthreads();
  for (int st = 512; st >= 128; st >>= 1){
    if (tid < st) red[tid] += red[tid+st];
    __syncthreads();
  }
  if (tid < 128){
    float val = (ssum > 0.f) ? red[tid]/ssum : 0.f;
    if (first) hg[g*128 + tid] = val;
    else       hg[g*128 + tid] += val;
  }
}

// out[g] = relu(hg[g] @ lin_w.T + lin_b) @ cls_w.T + cls_b   (all f32)
__global__ __launch_bounds__(256) void head(const float* __restrict__ hg,
    const float* __restrict__ lw, const float* __restrict__ lb,
    const float* __restrict__ cw, const float* __restrict__ cb,
    float* __restrict__ out){
  int g = blockIdx.x, tid = threadIdx.x;
  __shared__ float h[128];
  __shared__ float t1[256];
  __shared__ float red[256];
  if (tid < 128) h[tid] = hg[g*128 + tid];
  __syncthreads();
  const float* wr = lw + tid*128;
  float a = 0.f;
  for (int k = 0; k < 128; ++k) a += h[k]*wr[k];
  a = fmaxf(a + lb[tid], 0.f);
  t1[tid] = a;
  __syncthreads();
  int o = tid >> 7, j = tid & 127;
  float p = t1[j]*cw[o*256 + j] + t1[j+128]*cw[o*256 + j + 128];
  red[tid] = p; __syncthreads();
  for (int st = 64; st > 0; st >>= 1){
    if (j < st) red[tid] += red[tid+st];
    __syncthreads();
  }
  if (j == 0) out[g*2 + o] = red[tid] + cb[o];
}

extern "C" void kernel_launch(void* const* d_in, const int* in_sizes, int n_in,
                              void* d_out, int out_size, void* d_ws, size_t ws_size,
                              hipStream_t stream){
  const float* x   = (const float*)d_in[0];
  const int*   ei  = (const int*)d_in[1];
  const int* batch = (const int*)d_in[2];
  const float* w0  = (const float*)d_in[3];
  const float* b0  = (const float*)d_in[4];
  const float* w1  = (const float*)d_in[5];
  const float* b1  = (const float*)d_in[6];
  const float* w2  = (const float*)d_in[7];
  const float* b2  = (const float*)d_in[8];
  const float* gw  = (const float*)d_in[9];
  const float* gb  = (const float*)d_in[10];
  const float* lw  = (const float*)d_in[11];
  const float* lb  = (const float*)d_in[12];
  const float* cw  = (const float*)d_in[13];
  const float* cb  = (const float*)d_in[14];
  float* out = (float*)d_out;
  (void)in_sizes; (void)n_in; (void)out_size; (void)ws_size;

  char* ws = (char*)d_ws;
  size_t off = 0;
  auto alloc = [&](size_t bytes)->char*{
    char* p = ws + off;
    off = (off + bytes + 255) & ~(size_t)255;
    return p;
  };
  float* dis    = (float*)alloc((size_t)N_NODES*4);
  unsigned int* xb0  = (unsigned int*)alloc((size_t)N_NODES*64*4);  // bf16 x
  unsigned int* xw   = (unsigned int*)alloc((size_t)N_NODES*64*4);  // bf16 xw
  unsigned int* xbuf = (unsigned int*)alloc((size_t)N_NODES*64*4);  // bf16 agg out
  unsigned int* Wb0  = (unsigned int*)alloc((size_t)DIM*64*4);
  unsigned int* Wb1  = (unsigned int*)alloc((size_t)DIM*64*4);
  unsigned int* Wb2  = (unsigned int*)alloc((size_t)DIM*64*4);
  float* gate  = (float*)alloc((size_t)N_NODES*4);
  float* hg    = (float*)alloc((size_t)N_GRAPHS*DIM*4);
  int*   gs    = (int*)alloc((size_t)(N_GRAPHS+1)*4);
  int*   cnt   = (int*)alloc((size_t)N_NODES*4);
  int*   cursor= (int*)alloc((size_t)N_NODES*4);
  int*   offs  = (int*)alloc((size_t)(N_NODES+1)*4);
  int*   bsum  = (int*)alloc((size_t)SCAN_NB*4);
  int*   bpre  = (int*)alloc((size_t)SCAN_NB*4);
  int*   srcb  = (int*)alloc((size_t)N_EDGES*4);
  float* wn    = (float*)alloc((size_t)N_EDGES*4);

  const int T = 256;
  zero2_i32<<<(N_NODES+T-1)/T, T, 0, stream>>>(cnt, cursor, N_NODES);
  count_in<<<(N_EDGES+T-1)/T, T, 0, stream>>>(ei + N_EDGES, cnt);
  make_dis<<<(N_NODES+T-1)/T, T, 0, stream>>>(cnt, dis);
  scan_part<<<SCAN_NB, 256, 0, stream>>>(cnt, bsum, N_NODES);
  scan_mid <<<1, 256, 0, stream>>>(bsum, bpre, offs, SCAN_NB, N_NODES);
  scan_fin <<<SCAN_NB, 256, 0, stream>>>(cnt, bpre, offs, N_NODES);
  fill_csr<<<(N_EDGES+T-1)/T, T, 0, stream>>>(ei, dis, offs, cursor, srcb, wn);
  graph_starts<<<(N_NODES+T-1)/T, T, 0, stream>>>(batch, gs);

  // bf16 conversions
  f32_to_bf16<<<(N_NODES*64+T-1)/T, T, 0, stream>>>(x,  xb0, N_NODES*64);
  f32_to_bf16<<<(DIM*64+T-1)/T, T, 0, stream>>>(w0, Wb0, DIM*64);
  f32_to_bf16<<<(DIM*64+T-1)/T, T, 0, stream>>>(w1, Wb1, DIM*64);
  f32_to_bf16<<<(DIM*64+T-1)/T, T, 0, stream>>>(w2, Wb2, DIM*64);

  const unsigned int* xin = xb0;
  const unsigned int* Ws[3] = {Wb0, Wb1, Wb2};
  const float* Bs[3] = {b0, b1, b2};
  const int GEMM_BLKS = 512;           // 2048 waves
  for (int L = 0; L < 3; ++L){
    gemm_mfma<<<GEMM_BLKS, 256, 0, stream>>>(
        (const unsigned short*)xin, (const unsigned short*)Ws[L], Bs[L],
        (unsigned short*)xw, GEMM_BLKS*4);
    aggregate_bf<<<N_NODES/4, 256, 0, stream>>>(xw, offs, srcb, wn, dis, xbuf,
                                                gw, gb, gate);
    att_pool<<<N_GRAPHS, 1024, 0, stream>>>((const unsigned short*)xbuf, gate,
                                            gs, hg, (L==0) ? 1 : 0);
    xin = xbuf;
  }
  head<<<N_GRAPHS, 256, 0, stream>>>(hg, lw, lb, cw, cb, out);
}

// Round 6
// 301.985 us; speedup vs baseline: 2.5279x; 1.0298x over previous
//
#include <hip/hip_runtime.h>
#include <hip/hip_bf16.h>
#include <float.h>

#define N_NODES  50000
#define N_EDGES  640000
#define N_GRAPHS 128
#define DIM      128
#define CAP      64    // bucket slots per node; P(deg>=64) ~ 1e-24 per node

typedef __attribute__((ext_vector_type(8))) short bf16x8;
typedef __attribute__((ext_vector_type(4))) float f32x4;

__device__ __forceinline__ unsigned short f2bf(float f){
  unsigned int u = __float_as_uint(f);
  u += 0x7fffu + ((u >> 16) & 1u);     // round-to-nearest-even
  return (unsigned short)(u >> 16);
}
__device__ __forceinline__ float bf2f(unsigned short h){
  return __uint_as_float(((unsigned int)h) << 16);
}
__device__ __forceinline__ float2 up2(unsigned int p){
  return make_float2(__uint_as_float(p << 16),
                     __uint_as_float(p & 0xffff0000u));
}

__global__ void zero_i32(int* a, int n){
  int i = blockIdx.x*blockDim.x + threadIdx.x;
  if (i < n) a[i] = 0;
}

// one pass: count + place. srcb[c*64 + pos] = r
__global__ void scatter_src(const int* __restrict__ ei, int* __restrict__ cnt,
                            int* __restrict__ srcb){
  int e = blockIdx.x*blockDim.x + threadIdx.x;
  if (e >= N_EDGES) return;
  int r = ei[e];
  int c = ei[N_EDGES + e];
  int pos = atomicAdd(&cnt[c], 1);
  srcb[(c << 6) + pos] = r;
}

__global__ void make_dis(const int* __restrict__ cnt, float* __restrict__ dis){
  int i = blockIdx.x*blockDim.x + threadIdx.x;
  if (i < N_NODES) dis[i] = 1.0f / sqrtf((float)(cnt[i] + 1)); // +1 self-loop
}

// wave per node: wn[c*64+j] = dis[srcb[c*64+j]] * dis[c]
__global__ __launch_bounds__(256) void fill_wn(const int* __restrict__ srcb,
    const int* __restrict__ cnt, const float* __restrict__ dis,
    float* __restrict__ wnb){
  int node = blockIdx.x*4 + (threadIdx.x >> 6);
  if (node >= N_NODES) return;
  int lane = threadIdx.x & 63;
  int n = cnt[node];
  if (lane < n){
    int r = srcb[(node << 6) + lane];
    wnb[(node << 6) + lane] = dis[r] * dis[node];
  }
}

__global__ void graph_starts(const int* __restrict__ batch, int* __restrict__ gs){
  int i = blockIdx.x*blockDim.x + threadIdx.x;
  if (i >= N_NODES) return;
  int b  = batch[i];
  int bp = (i == 0) ? -1 : batch[i-1];
  for (int g = bp + 1; g <= b; ++g) gs[g] = i;
  if (i == N_NODES - 1)
    for (int g = b + 1; g <= N_GRAPHS; ++g) gs[g] = N_NODES;
}

// pack 2 f32 -> 1 uint of 2 bf16 (for x)
__global__ void f32_to_bf16(const float* __restrict__ in,
                            unsigned int* __restrict__ out, int n2){
  int i = blockIdx.x*blockDim.x + threadIdx.x;
  if (i < n2){
    float2 v = ((const float2*)in)[i];
    out[i] = (unsigned int)f2bf(v.x) | ((unsigned int)f2bf(v.y) << 16);
  }
}

// all three weight matrices in one launch (8192 float2 each)
__global__ void w3_to_bf16(const float* __restrict__ w0, const float* __restrict__ w1,
                           const float* __restrict__ w2, unsigned int* __restrict__ o0,
                           unsigned int* __restrict__ o1, unsigned int* __restrict__ o2){
  int i = blockIdx.x*blockDim.x + threadIdx.x;
  if (i >= 3*8192) return;
  int a = i >> 13, j = i & 8191;
  const float* src = (a == 0) ? w0 : (a == 1) ? w1 : w2;
  unsigned int* dst = (a == 0) ? o0 : (a == 1) ? o1 : o2;
  float2 v = ((const float2*)src)[j];
  dst[j] = (unsigned int)f2bf(v.x) | ((unsigned int)f2bf(v.y) << 16);
}

// MFMA GEMM: C[i][o] = bf16( sum_k A[i][k]*W[o][k] + bias[o] )
__global__ __launch_bounds__(256, 2) void gemm_mfma(
    const unsigned short* __restrict__ A, const unsigned short* __restrict__ Wb,
    const float* __restrict__ bias, unsigned short* __restrict__ C,
    int total_waves){
  int tid = threadIdx.x;
  int lane = tid & 63;
  int wid = blockIdx.x*4 + (tid >> 6);
  int l15 = lane & 15, l4 = lane >> 4;
  bf16x8 wf[8][4];
  #pragma unroll
  for (int ob = 0; ob < 8; ++ob)
    #pragma unroll
    for (int ks = 0; ks < 4; ++ks)
      wf[ob][ks] = *(const bf16x8*)&Wb[(ob*16 + l15)*128 + ks*32 + l4*8];
  float bv[8];
  #pragma unroll
  for (int ob = 0; ob < 8; ++ob) bv[ob] = bias[ob*16 + l15];

  for (int t = wid; t < N_NODES/16; t += total_waves){
    int row0 = t*16;
    bf16x8 af[4];
    #pragma unroll
    for (int ks = 0; ks < 4; ++ks)
      af[ks] = *(const bf16x8*)&A[(size_t)(row0 + l15)*128 + ks*32 + l4*8];
    f32x4 acc[8];
    #pragma unroll
    for (int ob = 0; ob < 8; ++ob) acc[ob] = (f32x4){0.f,0.f,0.f,0.f};
    #pragma unroll
    for (int ks = 0; ks < 4; ++ks)
      #pragma unroll
      for (int ob = 0; ob < 8; ++ob)
        acc[ob] = __builtin_amdgcn_mfma_f32_16x16x32_bf16(af[ks], wf[ob][ks],
                                                          acc[ob], 0, 0, 0);
    #pragma unroll
    for (int ob = 0; ob < 8; ++ob)
      #pragma unroll
      for (int r = 0; r < 4; ++r)
        C[(size_t)(row0 + l4*4 + r)*128 + ob*16 + l15] = f2bf(acc[ob][r] + bv[ob]);
  }
}

// one wave per node, bucket CSR: xout = relu(d^2*xw[c] + sum wn*xw[src]) (bf16)
// fused gate[c] = dot(xout[c], gw) + gb  (f32)
__global__ __launch_bounds__(256) void aggregate_bf(
    const unsigned int* __restrict__ xw,
    const int* __restrict__ cnt, const int* __restrict__ srcb,
    const float* __restrict__ wnb, const float* __restrict__ dis,
    unsigned int* __restrict__ xout, const float* __restrict__ gw,
    const float* __restrict__ gb, float* __restrict__ gate){
  int node = blockIdx.x*4 + (threadIdx.x >> 6);
  if (node >= N_NODES) return;
  int lane = threadIdx.x & 63;
  float d = dis[node];
  float2 vf = up2(xw[node*64 + lane]);
  float accx = d*d*vf.x, accy = d*d*vf.y;
  int n = cnt[node];
  int base = node << 6;
  int e = 0;
  for (; e + 8 <= n; e += 8){
    int   r0 = srcb[base+e  ], r1 = srcb[base+e+1], r2 = srcb[base+e+2], r3 = srcb[base+e+3];
    int   r4 = srcb[base+e+4], r5 = srcb[base+e+5], r6 = srcb[base+e+6], r7 = srcb[base+e+7];
    float w0 = wnb[base+e  ], w1 = wnb[base+e+1], w2 = wnb[base+e+2], w3 = wnb[base+e+3];
    float w4 = wnb[base+e+4], w5 = wnb[base+e+5], w6 = wnb[base+e+6], w7 = wnb[base+e+7];
    float2 u0 = up2(xw[r0*64 + lane]);
    float2 u1 = up2(xw[r1*64 + lane]);
    float2 u2 = up2(xw[r2*64 + lane]);
    float2 u3 = up2(xw[r3*64 + lane]);
    float2 u4 = up2(xw[r4*64 + lane]);
    float2 u5 = up2(xw[r5*64 + lane]);
    float2 u6 = up2(xw[r6*64 + lane]);
    float2 u7 = up2(xw[r7*64 + lane]);
    accx += w0*u0.x; accy += w0*u0.y;
    accx += w1*u1.x; accy += w1*u1.y;
    accx += w2*u2.x; accy += w2*u2.y;
    accx += w3*u3.x; accy += w3*u3.y;
    accx += w4*u4.x; accy += w4*u4.y;
    accx += w5*u5.x; accy += w5*u5.y;
    accx += w6*u6.x; accy += w6*u6.y;
    accx += w7*u7.x; accy += w7*u7.y;
  }
  for (; e < n; ++e){
    int r = srcb[base+e];
    float w = wnb[base+e];
    float2 u = up2(xw[r*64 + lane]);
    accx += w*u.x; accy += w*u.y;
  }
  accx = fmaxf(accx, 0.f);
  accy = fmaxf(accy, 0.f);
  xout[node*64 + lane] = (unsigned int)f2bf(accx) | ((unsigned int)f2bf(accy) << 16);
  float2 g = ((const float2*)gw)[lane];
  float p = accx*g.x + accy*g.y;
  #pragma unroll
  for (int o = 32; o > 0; o >>= 1) p += __shfl_xor(p, o, 64);
  if (lane == 0) gate[node] = p + gb[0];
}

// 4 blocks per graph: partial softmax-weighted feature sums (deterministic split)
__global__ __launch_bounds__(256) void att_pool_part(
    const unsigned short* __restrict__ x, const float* __restrict__ gate,
    const int* __restrict__ gs, float* __restrict__ hgp,
    float* __restrict__ ssum){
  int g = blockIdx.x >> 2, q = blockIdx.x & 3, tid = threadIdx.x;
  int s = gs[g], e = gs[g+1];
  __shared__ float red[256];
  // max over full graph range
  float m = -FLT_MAX;
  for (int i = s + tid; i < e; i += 256) m = fmaxf(m, gate[i]);
  red[tid] = m; __syncthreads();
  for (int st = 128; st > 0; st >>= 1){
    if (tid < st) red[tid] = fmaxf(red[tid], red[tid+st]);
    __syncthreads();
  }
  m = red[0]; __syncthreads();
  // sum of exp over full range
  float p = 0.f;
  for (int i = s + tid; i < e; i += 256) p += __expf(gate[i] - m);
  red[tid] = p; __syncthreads();
  for (int st = 128; st > 0; st >>= 1){
    if (tid < st) red[tid] += red[tid+st];
    __syncthreads();
  }
  if (tid == 0 && q == 0) ssum[g] = red[0];
  __syncthreads();
  // feature partial: rows s + (q*2+half) :: step 8
  int dim = tid & 127, half = tid >> 7;
  float acc = 0.f;
  for (int i = s + q*2 + half; i < e; i += 8)
    acc += __expf(gate[i] - m) * bf2f(x[(size_t)i*128 + dim]);
  red[tid] = acc; __syncthreads();
  if (tid < 128) hgp[(size_t)blockIdx.x*128 + tid] = red[tid] + red[tid+128];
}

// hg[g][d] (+)= (sum_q hgp[4g+q][d]) / ssum[g]
__global__ __launch_bounds__(256) void att_reduce(const float* __restrict__ hgp,
    const float* __restrict__ ssum, float* __restrict__ hg, int first){
  int idx = blockIdx.x*256 + threadIdx.x;
  if (idx >= N_GRAPHS*128) return;
  int g = idx >> 7, d = idx & 127;
  float p = hgp[(size_t)(4*g  )*128 + d] + hgp[(size_t)(4*g+1)*128 + d]
          + hgp[(size_t)(4*g+2)*128 + d] + hgp[(size_t)(4*g+3)*128 + d];
  float sv = ssum[g];
  float val = (sv > 0.f) ? p/sv : 0.f;
  hg[idx] = (first ? 0.f : hg[idx]) + val;
}

// out[g] = relu(hg[g] @ lin_w.T + lin_b) @ cls_w.T + cls_b   (all f32)
__global__ __launch_bounds__(256) void head(const float* __restrict__ hg,
    const float* __restrict__ lw, const float* __restrict__ lb,
    const float* __restrict__ cw, const float* __restrict__ cb,
    float* __restrict__ out){
  int g = blockIdx.x, tid = threadIdx.x;
  __shared__ float h[128];
  __shared__ float t1[256];
  __shared__ float red[256];
  if (tid < 128) h[tid] = hg[g*128 + tid];
  __syncthreads();
  const float* wr = lw + tid*128;
  float a = 0.f;
  for (int k = 0; k < 128; ++k) a += h[k]*wr[k];
  a = fmaxf(a + lb[tid], 0.f);
  t1[tid] = a;
  __syncthreads();
  int o = tid >> 7, j = tid & 127;
  float p = t1[j]*cw[o*256 + j] + t1[j+128]*cw[o*256 + j + 128];
  red[tid] = p; __syncthreads();
  for (int st = 64; st > 0; st >>= 1){
    if (j < st) red[tid] += red[tid+st];
    __syncthreads();
  }
  if (j == 0) out[g*2 + o] = red[tid] + cb[o];
}

extern "C" void kernel_launch(void* const* d_in, const int* in_sizes, int n_in,
                              void* d_out, int out_size, void* d_ws, size_t ws_size,
                              hipStream_t stream){
  const float* x   = (const float*)d_in[0];
  const int*   ei  = (const int*)d_in[1];
  const int* batch = (const int*)d_in[2];
  const float* w0  = (const float*)d_in[3];
  const float* b0  = (const float*)d_in[4];
  const float* w1  = (const float*)d_in[5];
  const float* b1  = (const float*)d_in[6];
  const float* w2  = (const float*)d_in[7];
  const float* b2  = (const float*)d_in[8];
  const float* gw  = (const float*)d_in[9];
  const float* gb  = (const float*)d_in[10];
  const float* lw  = (const float*)d_in[11];
  const float* lb  = (const float*)d_in[12];
  const float* cw  = (const float*)d_in[13];
  const float* cb  = (const float*)d_in[14];
  float* out = (float*)d_out;
  (void)in_sizes; (void)n_in; (void)out_size; (void)ws_size;

  char* ws = (char*)d_ws;
  size_t off = 0;
  auto alloc = [&](size_t bytes)->char*{
    char* p = ws + off;
    off = (off + bytes + 255) & ~(size_t)255;
    return p;
  };
  float* dis    = (float*)alloc((size_t)N_NODES*4);
  unsigned int* xb0  = (unsigned int*)alloc((size_t)N_NODES*64*4);  // bf16 x
  unsigned int* xw   = (unsigned int*)alloc((size_t)N_NODES*64*4);  // bf16 xw
  unsigned int* xbuf = (unsigned int*)alloc((size_t)N_NODES*64*4);  // bf16 agg out
  unsigned int* Wb0  = (unsigned int*)alloc((size_t)DIM*64*4);
  unsigned int* Wb1  = (unsigned int*)alloc((size_t)DIM*64*4);
  unsigned int* Wb2  = (unsigned int*)alloc((size_t)DIM*64*4);
  float* gate  = (float*)alloc((size_t)N_NODES*4);
  float* hg    = (float*)alloc((size_t)N_GRAPHS*DIM*4);
  float* hgp   = (float*)alloc((size_t)4*N_GRAPHS*DIM*4);
  float* ssum  = (float*)alloc((size_t)N_GRAPHS*4);
  int*   gs    = (int*)alloc((size_t)(N_GRAPHS+1)*4);
  int*   cnt   = (int*)alloc((size_t)N_NODES*4);
  int*   srcb  = (int*)alloc((size_t)N_NODES*CAP*4);
  float* wnb   = (float*)alloc((size_t)N_NODES*CAP*4);

  const int T = 256;
  zero_i32   <<<(N_NODES+T-1)/T, T, 0, stream>>>(cnt, N_NODES);
  scatter_src<<<(N_EDGES+T-1)/T, T, 0, stream>>>(ei, cnt, srcb);
  make_dis   <<<(N_NODES+T-1)/T, T, 0, stream>>>(cnt, dis);
  fill_wn    <<<N_NODES/4, T, 0, stream>>>(srcb, cnt, dis, wnb);
  graph_starts<<<(N_NODES+T-1)/T, T, 0, stream>>>(batch, gs);

  f32_to_bf16<<<(N_NODES*64+T-1)/T, T, 0, stream>>>(x, xb0, N_NODES*64);
  w3_to_bf16 <<<(3*8192+T-1)/T, T, 0, stream>>>(w0, w1, w2, Wb0, Wb1, Wb2);

  const unsigned int* xin = xb0;
  const unsigned int* Ws[3] = {Wb0, Wb1, Wb2};
  const float* Bs[3] = {b0, b1, b2};
  const int GEMM_BLKS = 512;           // 2048 waves
  for (int L = 0; L < 3; ++L){
    gemm_mfma<<<GEMM_BLKS, 256, 0, stream>>>(
        (const unsigned short*)xin, (const unsigned short*)Ws[L], Bs[L],
        (unsigned short*)xw, GEMM_BLKS*4);
    aggregate_bf<<<N_NODES/4, 256, 0, stream>>>(xw, cnt, srcb, wnb, dis, xbuf,
                                                gw, gb, gate);
    att_pool_part<<<4*N_GRAPHS, 256, 0, stream>>>((const unsigned short*)xbuf,
                                                  gate, gs, hgp, ssum);
    att_reduce<<<(N_GRAPHS*128+T-1)/T, T, 0, stream>>>(hgp, ssum, hg, (L==0)?1:0);
    xin = xbuf;
  }
  head<<<N_GRAPHS, 256, 0, stream>>>(hg, lw, lb, cw, cb, out);
}

// Round 7
// 285.535 us; speedup vs baseline: 2.6735x; 1.0576x over previous
//
#include <hip/hip_runtime.h>
#include <hip/hip_bf16.h>
#include <float.h>

#define N_NODES  50000
#define N_EDGES  640000
#define N_GRAPHS 128
#define DIM      128
#define CAP      64    // bucket slots per node; P(deg>=64) ~ 1e-24 per node
#define NSLICE   8     // destination slices (one per XCD)
#define SLICE_W  6250  // N_NODES / NSLICE
#define NCHUNK   256   // edge chunks
#define CHUNK_E  2500  // N_EDGES / NCHUNK

typedef __attribute__((ext_vector_type(8))) short bf16x8;
typedef __attribute__((ext_vector_type(4))) float f32x4;

__device__ __forceinline__ unsigned short f2bf(float f){
  unsigned int u = __float_as_uint(f);
  u += 0x7fffu + ((u >> 16) & 1u);     // round-to-nearest-even
  return (unsigned short)(u >> 16);
}
__device__ __forceinline__ float bf2f(unsigned short h){
  return __uint_as_float(((unsigned int)h) << 16);
}
__device__ __forceinline__ float2 up2(unsigned int p){
  return make_float2(__uint_as_float(p << 16),
                     __uint_as_float(p & 0xffff0000u));
}

__global__ void zero_i32(int* a, int n){
  int i = blockIdx.x*blockDim.x + threadIdx.x;
  if (i < n) a[i] = 0;
}

// XCD-sliced scatter: block (chunk = bid>>3, slice = bid&7) processes chunk's
// edges, keeps those with dest in slice. Under round-robin block->XCD dispatch
// each slice's srcb/cnt region stays in one XCD L2 (perf heuristic only).
__global__ __launch_bounds__(256) void scatter_sliced(
    const int* __restrict__ ei, int* __restrict__ cnt, int* __restrict__ srcb){
  int slice = blockIdx.x & (NSLICE-1);
  int chunk = blockIdx.x >> 3;
  int e0 = chunk * CHUNK_E;
  for (int e = e0 + threadIdx.x; e < e0 + CHUNK_E; e += 256){
    int c = ei[N_EDGES + e];
    if (c / SLICE_W == slice){
      int r = ei[e];
      int pos = atomicAdd(&cnt[c], 1);
      srcb[(c << 6) + pos] = r;
    }
  }
}

__global__ void make_dis(const int* __restrict__ cnt, float* __restrict__ dis){
  int i = blockIdx.x*blockDim.x + threadIdx.x;
  if (i < N_NODES) dis[i] = 1.0f / sqrtf((float)(cnt[i] + 1)); // +1 self-loop
}

__global__ void graph_starts(const int* __restrict__ batch, int* __restrict__ gs){
  int i = blockIdx.x*blockDim.x + threadIdx.x;
  if (i >= N_NODES) return;
  int b  = batch[i];
  int bp = (i == 0) ? -1 : batch[i-1];
  for (int g = bp + 1; g <= b; ++g) gs[g] = i;
  if (i == N_NODES - 1)
    for (int g = b + 1; g <= N_GRAPHS; ++g) gs[g] = N_NODES;
}

// pack 2 f32 -> 1 uint of 2 bf16 (for x)
__global__ void f32_to_bf16(const float* __restrict__ in,
                            unsigned int* __restrict__ out, int n2){
  int i = blockIdx.x*blockDim.x + threadIdx.x;
  if (i < n2){
    float2 v = ((const float2*)in)[i];
    out[i] = (unsigned int)f2bf(v.x) | ((unsigned int)f2bf(v.y) << 16);
  }
}

// all three weight matrices in one launch (8192 float2 each)
__global__ void w3_to_bf16(const float* __restrict__ w0, const float* __restrict__ w1,
                           const float* __restrict__ w2, unsigned int* __restrict__ o0,
                           unsigned int* __restrict__ o1, unsigned int* __restrict__ o2){
  int i = blockIdx.x*blockDim.x + threadIdx.x;
  if (i >= 3*8192) return;
  int a = i >> 13, j = i & 8191;
  const float* src = (a == 0) ? w0 : (a == 1) ? w1 : w2;
  unsigned int* dst = (a == 0) ? o0 : (a == 1) ? o1 : o2;
  float2 v = ((const float2*)src)[j];
  dst[j] = (unsigned int)f2bf(v.x) | ((unsigned int)f2bf(v.y) << 16);
}

// MFMA GEMM: C[i][o] = bf16( sum_k A[i][k]*W[o][k] + bias[o] )
__global__ __launch_bounds__(256, 2) void gemm_mfma(
    const unsigned short* __restrict__ A, const unsigned short* __restrict__ Wb,
    const float* __restrict__ bias, unsigned short* __restrict__ C,
    int total_waves){
  int tid = threadIdx.x;
  int lane = tid & 63;
  int wid = blockIdx.x*4 + (tid >> 6);
  int l15 = lane & 15, l4 = lane >> 4;
  bf16x8 wf[8][4];
  #pragma unroll
  for (int ob = 0; ob < 8; ++ob)
    #pragma unroll
    for (int ks = 0; ks < 4; ++ks)
      wf[ob][ks] = *(const bf16x8*)&Wb[(ob*16 + l15)*128 + ks*32 + l4*8];
  float bv[8];
  #pragma unroll
  for (int ob = 0; ob < 8; ++ob) bv[ob] = bias[ob*16 + l15];

  for (int t = wid; t < N_NODES/16; t += total_waves){
    int row0 = t*16;
    bf16x8 af[4];
    #pragma unroll
    for (int ks = 0; ks < 4; ++ks)
      af[ks] = *(const bf16x8*)&A[(size_t)(row0 + l15)*128 + ks*32 + l4*8];
    f32x4 acc[8];
    #pragma unroll
    for (int ob = 0; ob < 8; ++ob) acc[ob] = (f32x4){0.f,0.f,0.f,0.f};
    #pragma unroll
    for (int ks = 0; ks < 4; ++ks)
      #pragma unroll
      for (int ob = 0; ob < 8; ++ob)
        acc[ob] = __builtin_amdgcn_mfma_f32_16x16x32_bf16(af[ks], wf[ob][ks],
                                                          acc[ob], 0, 0, 0);
    #pragma unroll
    for (int ob = 0; ob < 8; ++ob)
      #pragma unroll
      for (int r = 0; r < 4; ++r)
        C[(size_t)(row0 + l4*4 + r)*128 + ob*16 + l15] = f2bf(acc[ob][r] + bv[ob]);
  }
}

// one wave per node, bucket CSR: xout = relu(d^2*xw[c] + sum dis[r]*d*xw[r]) (bf16)
// fused gate[c] = dot(xout[c], gw) + gb  (f32)
__global__ __launch_bounds__(256) void aggregate_bf(
    const unsigned int* __restrict__ xw,
    const int* __restrict__ cnt, const int* __restrict__ srcb,
    const float* __restrict__ dis,
    unsigned int* __restrict__ xout, const float* __restrict__ gw,
    const float* __restrict__ gb, float* __restrict__ gate){
  int node = blockIdx.x*4 + (threadIdx.x >> 6);
  if (node >= N_NODES) return;
  int lane = threadIdx.x & 63;
  float d = dis[node];
  float2 vf = up2(xw[node*64 + lane]);
  float accx = d*d*vf.x, accy = d*d*vf.y;
  int n = cnt[node];
  int base = node << 6;
  int e = 0;
  for (; e + 8 <= n; e += 8){
    int   r0 = srcb[base+e  ], r1 = srcb[base+e+1], r2 = srcb[base+e+2], r3 = srcb[base+e+3];
    int   r4 = srcb[base+e+4], r5 = srcb[base+e+5], r6 = srcb[base+e+6], r7 = srcb[base+e+7];
    float w0 = dis[r0]*d, w1 = dis[r1]*d, w2 = dis[r2]*d, w3 = dis[r3]*d;
    float w4 = dis[r4]*d, w5 = dis[r5]*d, w6 = dis[r6]*d, w7 = dis[r7]*d;
    float2 u0 = up2(xw[r0*64 + lane]);
    float2 u1 = up2(xw[r1*64 + lane]);
    float2 u2 = up2(xw[r2*64 + lane]);
    float2 u3 = up2(xw[r3*64 + lane]);
    float2 u4 = up2(xw[r4*64 + lane]);
    float2 u5 = up2(xw[r5*64 + lane]);
    float2 u6 = up2(xw[r6*64 + lane]);
    float2 u7 = up2(xw[r7*64 + lane]);
    accx += w0*u0.x; accy += w0*u0.y;
    accx += w1*u1.x; accy += w1*u1.y;
    accx += w2*u2.x; accy += w2*u2.y;
    accx += w3*u3.x; accy += w3*u3.y;
    accx += w4*u4.x; accy += w4*u4.y;
    accx += w5*u5.x; accy += w5*u5.y;
    accx += w6*u6.x; accy += w6*u6.y;
    accx += w7*u7.x; accy += w7*u7.y;
  }
  for (; e < n; ++e){
    int r = srcb[base+e];
    float w = dis[r]*d;
    float2 u = up2(xw[r*64 + lane]);
    accx += w*u.x; accy += w*u.y;
  }
  accx = fmaxf(accx, 0.f);
  accy = fmaxf(accy, 0.f);
  xout[node*64 + lane] = (unsigned int)f2bf(accx) | ((unsigned int)f2bf(accy) << 16);
  float2 g = ((const float2*)gw)[lane];
  float p = accx*g.x + accy*g.y;
  #pragma unroll
  for (int o = 32; o > 0; o >>= 1) p += __shfl_xor(p, o, 64);
  if (lane == 0) gate[node] = p + gb[0];
}

// 4 blocks per graph: partial softmax-weighted feature sums (deterministic split)
__global__ __launch_bounds__(256) void att_pool_part(
    const unsigned short* __restrict__ x, const float* __restrict__ gate,
    const int* __restrict__ gs, float* __restrict__ hgp,
    float* __restrict__ ssum){
  int g = blockIdx.x >> 2, q = blockIdx.x & 3, tid = threadIdx.x;
  int s = gs[g], e = gs[g+1];
  __shared__ float red[256];
  float m = -FLT_MAX;
  for (int i = s + tid; i < e; i += 256) m = fmaxf(m, gate[i]);
  red[tid] = m; __syncthreads();
  for (int st = 128; st > 0; st >>= 1){
    if (tid < st) red[tid] = fmaxf(red[tid], red[tid+st]);
    __syncthreads();
  }
  m = red[0]; __syncthreads();
  float p = 0.f;
  for (int i = s + tid; i < e; i += 256) p += __expf(gate[i] - m);
  red[tid] = p; __syncthreads();
  for (int st = 128; st > 0; st >>= 1){
    if (tid < st) red[tid] += red[tid+st];
    __syncthreads();
  }
  if (tid == 0 && q == 0) ssum[g] = red[0];
  __syncthreads();
  int dim = tid & 127, half = tid >> 7;
  float acc = 0.f;
  for (int i = s + q*2 + half; i < e; i += 8)
    acc += __expf(gate[i] - m) * bf2f(x[(size_t)i*128 + dim]);
  red[tid] = acc; __syncthreads();
  if (tid < 128) hgp[(size_t)blockIdx.x*128 + tid] = red[tid] + red[tid+128];
}

// hg[g][d] (+)= (sum_q hgp[4g+q][d]) / ssum[g]
__global__ __launch_bounds__(256) void att_reduce(const float* __restrict__ hgp,
    const float* __restrict__ ssum, float* __restrict__ hg, int first){
  int idx = blockIdx.x*256 + threadIdx.x;
  if (idx >= N_GRAPHS*128) return;
  int g = idx >> 7, d = idx & 127;
  float p = hgp[(size_t)(4*g  )*128 + d] + hgp[(size_t)(4*g+1)*128 + d]
          + hgp[(size_t)(4*g+2)*128 + d] + hgp[(size_t)(4*g+3)*128 + d];
  float sv = ssum[g];
  float val = (sv > 0.f) ? p/sv : 0.f;
  hg[idx] = (first ? 0.f : hg[idx]) + val;
}

// out[g] = relu(hg[g] @ lin_w.T + lin_b) @ cls_w.T + cls_b   (all f32)
__global__ __launch_bounds__(256) void head(const float* __restrict__ hg,
    const float* __restrict__ lw, const float* __restrict__ lb,
    const float* __restrict__ cw, const float* __restrict__ cb,
    float* __restrict__ out){
  int g = blockIdx.x, tid = threadIdx.x;
  __shared__ float h[128];
  __shared__ float t1[256];
  __shared__ float red[256];
  if (tid < 128) h[tid] = hg[g*128 + tid];
  __syncthreads();
  const float* wr = lw + tid*128;
  float a = 0.f;
  for (int k = 0; k < 128; ++k) a += h[k]*wr[k];
  a = fmaxf(a + lb[tid], 0.f);
  t1[tid] = a;
  __syncthreads();
  int o = tid >> 7, j = tid & 127;
  float p = t1[j]*cw[o*256 + j] + t1[j+128]*cw[o*256 + j + 128];
  red[tid] = p; __syncthreads();
  for (int st = 64; st > 0; st >>= 1){
    if (j < st) red[tid] += red[tid+st];
    __syncthreads();
  }
  if (j == 0) out[g*2 + o] = red[tid] + cb[o];
}

extern "C" void kernel_launch(void* const* d_in, const int* in_sizes, int n_in,
                              void* d_out, int out_size, void* d_ws, size_t ws_size,
                              hipStream_t stream){
  const float* x   = (const float*)d_in[0];
  const int*   ei  = (const int*)d_in[1];
  const int* batch = (const int*)d_in[2];
  const float* w0  = (const float*)d_in[3];
  const float* b0  = (const float*)d_in[4];
  const float* w1  = (const float*)d_in[5];
  const float* b1  = (const float*)d_in[6];
  const float* w2  = (const float*)d_in[7];
  const float* b2  = (const float*)d_in[8];
  const float* gw  = (const float*)d_in[9];
  const float* gb  = (const float*)d_in[10];
  const float* lw  = (const float*)d_in[11];
  const float* lb  = (const float*)d_in[12];
  const float* cw  = (const float*)d_in[13];
  const float* cb  = (const float*)d_in[14];
  float* out = (float*)d_out;
  (void)in_sizes; (void)n_in; (void)out_size; (void)ws_size;

  char* ws = (char*)d_ws;
  size_t off = 0;
  auto alloc = [&](size_t bytes)->char*{
    char* p = ws + off;
    off = (off + bytes + 255) & ~(size_t)255;
    return p;
  };
  float* dis    = (float*)alloc((size_t)N_NODES*4);
  unsigned int* xb0  = (unsigned int*)alloc((size_t)N_NODES*64*4);  // bf16 x
  unsigned int* xw   = (unsigned int*)alloc((size_t)N_NODES*64*4);  // bf16 xw
  unsigned int* xbuf = (unsigned int*)alloc((size_t)N_NODES*64*4);  // bf16 agg out
  unsigned int* Wb0  = (unsigned int*)alloc((size_t)DIM*64*4);
  unsigned int* Wb1  = (unsigned int*)alloc((size_t)DIM*64*4);
  unsigned int* Wb2  = (unsigned int*)alloc((size_t)DIM*64*4);
  float* gate  = (float*)alloc((size_t)N_NODES*4);
  float* hg    = (float*)alloc((size_t)N_GRAPHS*DIM*4);
  float* hgp   = (float*)alloc((size_t)4*N_GRAPHS*DIM*4);
  float* ssum  = (float*)alloc((size_t)N_GRAPHS*4);
  int*   gs    = (int*)alloc((size_t)(N_GRAPHS+1)*4);
  int*   cnt   = (int*)alloc((size_t)N_NODES*4);
  int*   srcb  = (int*)alloc((size_t)N_NODES*CAP*4);

  const int T = 256;
  zero_i32      <<<(N_NODES+T-1)/T, T, 0, stream>>>(cnt, N_NODES);
  scatter_sliced<<<NCHUNK*NSLICE, T, 0, stream>>>(ei, cnt, srcb);
  make_dis      <<<(N_NODES+T-1)/T, T, 0, stream>>>(cnt, dis);
  graph_starts  <<<(N_NODES+T-1)/T, T, 0, stream>>>(batch, gs);

  f32_to_bf16<<<(N_NODES*64+T-1)/T, T, 0, stream>>>(x, xb0, N_NODES*64);
  w3_to_bf16 <<<(3*8192+T-1)/T, T, 0, stream>>>(w0, w1, w2, Wb0, Wb1, Wb2);

  const unsigned int* xin = xb0;
  const unsigned int* Ws[3] = {Wb0, Wb1, Wb2};
  const float* Bs[3] = {b0, b1, b2};
  const int GEMM_BLKS = 512;           // 2048 waves
  for (int L = 0; L < 3; ++L){
    gemm_mfma<<<GEMM_BLKS, 256, 0, stream>>>(
        (const unsigned short*)xin, (const unsigned short*)Ws[L], Bs[L],
        (unsigned short*)xw, GEMM_BLKS*4);
    aggregate_bf<<<N_NODES/4, 256, 0, stream>>>(xw, cnt, srcb, dis, xbuf,
                                                gw, gb, gate);
    att_pool_part<<<4*N_GRAPHS, 256, 0, stream>>>((const unsigned short*)xbuf,
                                                  gate, gs, hgp, ssum);
    att_reduce<<<(N_GRAPHS*128+T-1)/T, T, 0, stream>>>(hgp, ssum, hg, (L==0)?1:0);
    xin = xbuf;
  }
  head<<<N_GRAPHS, 256, 0, stream>>>(hg, lw, lb, cw, cb, out);
}

// Round 8
// 267.803 us; speedup vs baseline: 2.8506x; 1.0662x over previous
//
#include <hip/hip_runtime.h>
#include <hip/hip_bf16.h>
#include <float.h>

#define N_NODES  50000
#define N_EDGES  640000
#define N_GRAPHS 128
#define DIM      128
#define CAP      64    // bucket slots per node; P(deg>=64) ~ 1e-24 per node
#define NSLICE   8     // destination slices (one per XCD)
#define SLICE_W  6250  // N_NODES / NSLICE
#define NCHUNK   256   // edge chunks
#define CHUNK_E  2500  // N_EDGES / NCHUNK

typedef __attribute__((ext_vector_type(8))) short bf16x8;
typedef __attribute__((ext_vector_type(4))) float f32x4;

__device__ __forceinline__ unsigned short f2bf(float f){
  unsigned int u = __float_as_uint(f);
  u += 0x7fffu + ((u >> 16) & 1u);     // round-to-nearest-even
  return (unsigned short)(u >> 16);
}
__device__ __forceinline__ float bf2f(unsigned short h){
  return __uint_as_float(((unsigned int)h) << 16);
}
__device__ __forceinline__ float2 up2(unsigned int p){
  return make_float2(__uint_as_float(p << 16),
                     __uint_as_float(p & 0xffff0000u));
}

__global__ void zero_i32(int* a, int n){
  int i = blockIdx.x*blockDim.x + threadIdx.x;
  if (i < n) a[i] = 0;
}

// XCD-sliced scatter: block (chunk = bid>>3, slice = bid&7) processes chunk's
// edges, keeps those with dest in slice (L2-locality heuristic only).
__global__ __launch_bounds__(256) void scatter_sliced(
    const int* __restrict__ ei, int* __restrict__ cnt, int* __restrict__ srcb){
  int slice = blockIdx.x & (NSLICE-1);
  int chunk = blockIdx.x >> 3;
  int e0 = chunk * CHUNK_E;
  for (int e = e0 + threadIdx.x; e < e0 + CHUNK_E; e += 256){
    int c = ei[N_EDGES + e];
    if (c / SLICE_W == slice){
      int r = ei[e];
      int pos = atomicAdd(&cnt[c], 1);
      srcb[(c << 6) + pos] = r;
    }
  }
}

__global__ void make_dis(const int* __restrict__ cnt, float* __restrict__ dis){
  int i = blockIdx.x*blockDim.x + threadIdx.x;
  if (i < N_NODES) dis[i] = 1.0f / sqrtf((float)(cnt[i] + 1)); // +1 self-loop
}

__global__ void graph_starts(const int* __restrict__ batch, int* __restrict__ gs){
  int i = blockIdx.x*blockDim.x + threadIdx.x;
  if (i >= N_NODES) return;
  int b  = batch[i];
  int bp = (i == 0) ? -1 : batch[i-1];
  for (int g = bp + 1; g <= b; ++g) gs[g] = i;
  if (i == N_NODES - 1)
    for (int g = b + 1; g <= N_GRAPHS; ++g) gs[g] = N_NODES;
}

// pack 2 f32 -> 1 uint of 2 bf16 (for x)
__global__ void f32_to_bf16(const float* __restrict__ in,
                            unsigned int* __restrict__ out, int n2){
  int i = blockIdx.x*blockDim.x + threadIdx.x;
  if (i < n2){
    float2 v = ((const float2*)in)[i];
    out[i] = (unsigned int)f2bf(v.x) | ((unsigned int)f2bf(v.y) << 16);
  }
}

// all three weight matrices in one launch (8192 float2 each)
__global__ void w3_to_bf16(const float* __restrict__ w0, const float* __restrict__ w1,
                           const float* __restrict__ w2, unsigned int* __restrict__ o0,
                           unsigned int* __restrict__ o1, unsigned int* __restrict__ o2){
  int i = blockIdx.x*blockDim.x + threadIdx.x;
  if (i >= 3*8192) return;
  int a = i >> 13, j = i & 8191;
  const float* src = (a == 0) ? w0 : (a == 1) ? w1 : w2;
  unsigned int* dst = (a == 0) ? o0 : (a == 1) ? o1 : o2;
  float2 v = ((const float2*)src)[j];
  dst[j] = (unsigned int)f2bf(v.x) | ((unsigned int)f2bf(v.y) << 16);
}

// MFMA GEMM: C[i][o] = bf16( sum_k A[i][k]*W[o][k] + bias[o] )
__global__ __launch_bounds__(256, 2) void gemm_mfma(
    const unsigned short* __restrict__ A, const unsigned short* __restrict__ Wb,
    const float* __restrict__ bias, unsigned short* __restrict__ C,
    int total_waves){
  int tid = threadIdx.x;
  int lane = tid & 63;
  int wid = blockIdx.x*4 + (tid >> 6);
  int l15 = lane & 15, l4 = lane >> 4;
  bf16x8 wf[8][4];
  #pragma unroll
  for (int ob = 0; ob < 8; ++ob)
    #pragma unroll
    for (int ks = 0; ks < 4; ++ks)
      wf[ob][ks] = *(const bf16x8*)&Wb[(ob*16 + l15)*128 + ks*32 + l4*8];
  float bv[8];
  #pragma unroll
  for (int ob = 0; ob < 8; ++ob) bv[ob] = bias[ob*16 + l15];

  for (int t = wid; t < N_NODES/16; t += total_waves){
    int row0 = t*16;
    bf16x8 af[4];
    #pragma unroll
    for (int ks = 0; ks < 4; ++ks)
      af[ks] = *(const bf16x8*)&A[(size_t)(row0 + l15)*128 + ks*32 + l4*8];
    f32x4 acc[8];
    #pragma unroll
    for (int ob = 0; ob < 8; ++ob) acc[ob] = (f32x4){0.f,0.f,0.f,0.f};
    #pragma unroll
    for (int ks = 0; ks < 4; ++ks)
      #pragma unroll
      for (int ob = 0; ob < 8; ++ob)
        acc[ob] = __builtin_amdgcn_mfma_f32_16x16x32_bf16(af[ks], wf[ob][ks],
                                                          acc[ob], 0, 0, 0);
    #pragma unroll
    for (int ob = 0; ob < 8; ++ob)
      #pragma unroll
      for (int r = 0; r < 4; ++r)
        C[(size_t)(row0 + l4*4 + r)*128 + ob*16 + l15] = f2bf(acc[ob][r] + bv[ob]);
  }
}

// 4 nodes per wave, 16 lanes per node, uint4 (8 bf16) per lane.
// xout = relu(d^2*xw[c] + sum dis[r]*d*xw[r]);  gate = dot(xout, gw) + gb
__global__ __launch_bounds__(256) void aggregate_bf(
    const uint4* __restrict__ xw4,
    const int* __restrict__ cnt, const int* __restrict__ srcb,
    const float* __restrict__ dis,
    uint4* __restrict__ xout4, const float* __restrict__ gw,
    const float* __restrict__ gb, float* __restrict__ gate){
  int tid  = threadIdx.x;
  int lane = tid & 63;
  int wv   = tid >> 6;
  int sub  = lane >> 4, l16 = lane & 15;
  int node = (blockIdx.x*4 + wv)*4 + sub;   // grid = N_NODES/16, exact
  float d  = dis[node];
  int   n  = cnt[node];
  int base = node << 6;
  uint4 v  = xw4[node*16 + l16];
  float dd = d*d;
  float acc[8];
  {
    float2 a0 = up2(v.x), a1 = up2(v.y), a2 = up2(v.z), a3 = up2(v.w);
    acc[0]=dd*a0.x; acc[1]=dd*a0.y; acc[2]=dd*a1.x; acc[3]=dd*a1.y;
    acc[4]=dd*a2.x; acc[5]=dd*a2.y; acc[6]=dd*a3.x; acc[7]=dd*a3.y;
  }
  int nmax = n;
  nmax = max(nmax, __shfl_xor(nmax, 16, 64));
  nmax = max(nmax, __shfl_xor(nmax, 32, 64));
  for (int e = 0; e < nmax; e += 4){
    int r0, r1, r2, r3;
    float w0, w1, w2, w3;
    {
      bool v0 = e   < n, v1 = e+1 < n, v2 = e+2 < n, v3 = e+3 < n;
      int  s0 = srcb[base+e], s1 = srcb[base+e+1],
           s2 = srcb[base+e+2], s3 = srcb[base+e+3];   // slack-padded, in-bounds
      r0 = v0 ? s0 : node;  r1 = v1 ? s1 : node;
      r2 = v2 ? s2 : node;  r3 = v3 ? s3 : node;
      w0 = v0 ? dis[r0]*d : 0.f;  w1 = v1 ? dis[r1]*d : 0.f;
      w2 = v2 ? dis[r2]*d : 0.f;  w3 = v3 ? dis[r3]*d : 0.f;
    }
    uint4 u0 = xw4[r0*16 + l16];
    uint4 u1 = xw4[r1*16 + l16];
    uint4 u2 = xw4[r2*16 + l16];
    uint4 u3 = xw4[r3*16 + l16];
    {
      float2 b0=up2(u0.x), b1=up2(u0.y), b2=up2(u0.z), b3=up2(u0.w);
      acc[0]+=w0*b0.x; acc[1]+=w0*b0.y; acc[2]+=w0*b1.x; acc[3]+=w0*b1.y;
      acc[4]+=w0*b2.x; acc[5]+=w0*b2.y; acc[6]+=w0*b3.x; acc[7]+=w0*b3.y;
    }
    {
      float2 b0=up2(u1.x), b1=up2(u1.y), b2=up2(u1.z), b3=up2(u1.w);
      acc[0]+=w1*b0.x; acc[1]+=w1*b0.y; acc[2]+=w1*b1.x; acc[3]+=w1*b1.y;
      acc[4]+=w1*b2.x; acc[5]+=w1*b2.y; acc[6]+=w1*b3.x; acc[7]+=w1*b3.y;
    }
    {
      float2 b0=up2(u2.x), b1=up2(u2.y), b2=up2(u2.z), b3=up2(u2.w);
      acc[0]+=w2*b0.x; acc[1]+=w2*b0.y; acc[2]+=w2*b1.x; acc[3]+=w2*b1.y;
      acc[4]+=w2*b2.x; acc[5]+=w2*b2.y; acc[6]+=w2*b3.x; acc[7]+=w2*b3.y;
    }
    {
      float2 b0=up2(u3.x), b1=up2(u3.y), b2=up2(u3.z), b3=up2(u3.w);
      acc[0]+=w3*b0.x; acc[1]+=w3*b0.y; acc[2]+=w3*b1.x; acc[3]+=w3*b1.y;
      acc[4]+=w3*b2.x; acc[5]+=w3*b2.y; acc[6]+=w3*b3.x; acc[7]+=w3*b3.y;
    }
  }
  #pragma unroll
  for (int i = 0; i < 8; ++i) acc[i] = fmaxf(acc[i], 0.f);
  uint4 o;
  o.x = (unsigned int)f2bf(acc[0]) | ((unsigned int)f2bf(acc[1]) << 16);
  o.y = (unsigned int)f2bf(acc[2]) | ((unsigned int)f2bf(acc[3]) << 16);
  o.z = (unsigned int)f2bf(acc[4]) | ((unsigned int)f2bf(acc[5]) << 16);
  o.w = (unsigned int)f2bf(acc[6]) | ((unsigned int)f2bf(acc[7]) << 16);
  xout4[node*16 + l16] = o;
  const float4* gw4 = (const float4*)gw;
  float4 g0 = gw4[l16*2], g1 = gw4[l16*2 + 1];
  float p = acc[0]*g0.x + acc[1]*g0.y + acc[2]*g0.z + acc[3]*g0.w
          + acc[4]*g1.x + acc[5]*g1.y + acc[6]*g1.z + acc[7]*g1.w;
  p += __shfl_xor(p, 1, 64);
  p += __shfl_xor(p, 2, 64);
  p += __shfl_xor(p, 4, 64);
  p += __shfl_xor(p, 8, 64);
  if (l16 == 0) gate[node] = p + gb[0];
}

// 4 blocks per graph: partial softmax-weighted feature sums (deterministic split)
__global__ __launch_bounds__(256) void att_pool_part(
    const unsigned short* __restrict__ x, const float* __restrict__ gate,
    const int* __restrict__ gs, float* __restrict__ hgp,
    float* __restrict__ ssum){
  int g = blockIdx.x >> 2, q = blockIdx.x & 3, tid = threadIdx.x;
  int s = gs[g], e = gs[g+1];
  __shared__ float red[256];
  float m = -FLT_MAX;
  for (int i = s + tid; i < e; i += 256) m = fmaxf(m, gate[i]);
  red[tid] = m; __syncthreads();
  for (int st = 128; st > 0; st >>= 1){
    if (tid < st) red[tid] = fmaxf(red[tid], red[tid+st]);
    __syncthreads();
  }
  m = red[0]; __syncthreads();
  float p = 0.f;
  for (int i = s + tid; i < e; i += 256) p += __expf(gate[i] - m);
  red[tid] = p; __syncthreads();
  for (int st = 128; st > 0; st >>= 1){
    if (tid < st) red[tid] += red[tid+st];
    __syncthreads();
  }
  if (tid == 0 && q == 0) ssum[g] = red[0];
  __syncthreads();
  int dim = tid & 127, half = tid >> 7;
  float acc = 0.f;
  for (int i = s + q*2 + half; i < e; i += 8)
    acc += __expf(gate[i] - m) * bf2f(x[(size_t)i*128 + dim]);
  red[tid] = acc; __syncthreads();
  if (tid < 128) hgp[(size_t)blockIdx.x*128 + tid] = red[tid] + red[tid+128];
}

// hg[g][d] (+)= (sum_q hgp[4g+q][d]) / ssum[g]
__global__ __launch_bounds__(256) void att_reduce(const float* __restrict__ hgp,
    const float* __restrict__ ssum, float* __restrict__ hg, int first){
  int idx = blockIdx.x*256 + threadIdx.x;
  if (idx >= N_GRAPHS*128) return;
  int g = idx >> 7, d = idx & 127;
  float p = hgp[(size_t)(4*g  )*128 + d] + hgp[(size_t)(4*g+1)*128 + d]
          + hgp[(size_t)(4*g+2)*128 + d] + hgp[(size_t)(4*g+3)*128 + d];
  float sv = ssum[g];
  float val = (sv > 0.f) ? p/sv : 0.f;
  hg[idx] = (first ? 0.f : hg[idx]) + val;
}

// out[g] = relu(hg[g] @ lin_w.T + lin_b) @ cls_w.T + cls_b   (all f32)
__global__ __launch_bounds__(256) void head(const float* __restrict__ hg,
    const float* __restrict__ lw, const float* __restrict__ lb,
    const float* __restrict__ cw, const float* __restrict__ cb,
    float* __restrict__ out){
  int g = blockIdx.x, tid = threadIdx.x;
  __shared__ float h[128];
  __shared__ float t1[256];
  __shared__ float red[256];
  if (tid < 128) h[tid] = hg[g*128 + tid];
  __syncthreads();
  const float* wr = lw + tid*128;
  float a = 0.f;
  for (int k = 0; k < 128; ++k) a += h[k]*wr[k];
  a = fmaxf(a + lb[tid], 0.f);
  t1[tid] = a;
  __syncthreads();
  int o = tid >> 7, j = tid & 127;
  float p = t1[j]*cw[o*256 + j] + t1[j+128]*cw[o*256 + j + 128];
  red[tid] = p; __syncthreads();
  for (int st = 64; st > 0; st >>= 1){
    if (j < st) red[tid] += red[tid+st];
    __syncthreads();
  }
  if (j == 0) out[g*2 + o] = red[tid] + cb[o];
}

extern "C" void kernel_launch(void* const* d_in, const int* in_sizes, int n_in,
                              void* d_out, int out_size, void* d_ws, size_t ws_size,
                              hipStream_t stream){
  const float* x   = (const float*)d_in[0];
  const int*   ei  = (const int*)d_in[1];
  const int* batch = (const int*)d_in[2];
  const float* w0  = (const float*)d_in[3];
  const float* b0  = (const float*)d_in[4];
  const float* w1  = (const float*)d_in[5];
  const float* b1  = (const float*)d_in[6];
  const float* w2  = (const float*)d_in[7];
  const float* b2  = (const float*)d_in[8];
  const float* gw  = (const float*)d_in[9];
  const float* gb  = (const float*)d_in[10];
  const float* lw  = (const float*)d_in[11];
  const float* lb  = (const float*)d_in[12];
  const float* cw  = (const float*)d_in[13];
  const float* cb  = (const float*)d_in[14];
  float* out = (float*)d_out;
  (void)in_sizes; (void)n_in; (void)out_size; (void)ws_size;

  char* ws = (char*)d_ws;
  size_t off = 0;
  auto alloc = [&](size_t bytes)->char*{
    char* p = ws + off;
    off = (off + bytes + 255) & ~(size_t)255;
    return p;
  };
  float* dis    = (float*)alloc((size_t)N_NODES*4);
  unsigned int* xb0  = (unsigned int*)alloc((size_t)N_NODES*64*4);  // bf16 x
  unsigned int* xw   = (unsigned int*)alloc((size_t)N_NODES*64*4);  // bf16 xw
  unsigned int* xbuf = (unsigned int*)alloc((size_t)N_NODES*64*4);  // bf16 agg out
  unsigned int* Wb0  = (unsigned int*)alloc((size_t)DIM*64*4);
  unsigned int* Wb1  = (unsigned int*)alloc((size_t)DIM*64*4);
  unsigned int* Wb2  = (unsigned int*)alloc((size_t)DIM*64*4);
  float* gate  = (float*)alloc((size_t)N_NODES*4);
  float* hg    = (float*)alloc((size_t)N_GRAPHS*DIM*4);
  float* hgp   = (float*)alloc((size_t)4*N_GRAPHS*DIM*4);
  float* ssum  = (float*)alloc((size_t)N_GRAPHS*4);
  int*   gs    = (int*)alloc((size_t)(N_GRAPHS+1)*4);
  int*   cnt   = (int*)alloc((size_t)N_NODES*4);
  int*   srcb  = (int*)alloc(((size_t)N_NODES*CAP + 64)*4);  // +slack for spec reads

  const int T = 256;
  zero_i32      <<<(N_NODES+T-1)/T, T, 0, stream>>>(cnt, N_NODES);
  scatter_sliced<<<NCHUNK*NSLICE, T, 0, stream>>>(ei, cnt, srcb);
  make_dis      <<<(N_NODES+T-1)/T, T, 0, stream>>>(cnt, dis);
  graph_starts  <<<(N_NODES+T-1)/T, T, 0, stream>>>(batch, gs);

  f32_to_bf16<<<(N_NODES*64+T-1)/T, T, 0, stream>>>(x, xb0, N_NODES*64);
  w3_to_bf16 <<<(3*8192+T-1)/T, T, 0, stream>>>(w0, w1, w2, Wb0, Wb1, Wb2);

  const unsigned int* xin = xb0;
  const unsigned int* Ws[3] = {Wb0, Wb1, Wb2};
  const float* Bs[3] = {b0, b1, b2};
  const int GEMM_BLKS = 512;           // 2048 waves
  for (int L = 0; L < 3; ++L){
    gemm_mfma<<<GEMM_BLKS, 256, 0, stream>>>(
        (const unsigned short*)xin, (const unsigned short*)Ws[L], Bs[L],
        (unsigned short*)xw, GEMM_BLKS*4);
    aggregate_bf<<<N_NODES/16, 256, 0, stream>>>((const uint4*)xw, cnt, srcb,
                                                 dis, (uint4*)xbuf, gw, gb, gate);
    att_pool_part<<<4*N_GRAPHS, 256, 0, stream>>>((const unsigned short*)xbuf,
                                                  gate, gs, hgp, ssum);
    att_reduce<<<(N_GRAPHS*128+T-1)/T, T, 0, stream>>>(hgp, ssum, hg, (L==0)?1:0);
    xin = xbuf;
  }
  head<<<N_GRAPHS, 256, 0, stream>>>(hg, lw, lb, cw, cb, out);
}

// Round 9
// 248.341 us; speedup vs baseline: 3.0739x; 1.0784x over previous
//
#include <hip/hip_runtime.h>
#include <hip/hip_bf16.h>
#include <float.h>

#define N_NODES  50000
#define N_EDGES  640000
#define N_GRAPHS 128
#define DIM      128
#define CAP      64    // bucket slots per node; P(deg>=64) ~ 1e-24 per node
#define NSLICE   8     // destination slices (one per XCD)
#define SLICE_W  6250  // N_NODES / NSLICE
#define NCHUNK   256   // edge chunks
#define CHUNK_E  2500  // N_EDGES / NCHUNK

typedef __attribute__((ext_vector_type(8))) short bf16x8;
typedef __attribute__((ext_vector_type(4))) float f32x4;

__device__ __forceinline__ unsigned short f2bf(float f){
  unsigned int u = __float_as_uint(f);
  u += 0x7fffu + ((u >> 16) & 1u);     // round-to-nearest-even
  return (unsigned short)(u >> 16);
}
__device__ __forceinline__ float bf2f(unsigned short h){
  return __uint_as_float(((unsigned int)h) << 16);
}
__device__ __forceinline__ float2 up2(unsigned int p){
  return make_float2(__uint_as_float(p << 16),
                     __uint_as_float(p & 0xffff0000u));
}

__global__ void zero_i32(int* a, int n){
  int i = blockIdx.x*blockDim.x + threadIdx.x;
  if (i < n) a[i] = 0;
}

// XCD-sliced scatter (L2-locality heuristic only; correctness order-free)
__global__ __launch_bounds__(256) void scatter_sliced(
    const int* __restrict__ ei, int* __restrict__ cnt, int* __restrict__ srcb){
  int slice = blockIdx.x & (NSLICE-1);
  int chunk = blockIdx.x >> 3;
  int e0 = chunk * CHUNK_E;
  for (int e = e0 + threadIdx.x; e < e0 + CHUNK_E; e += 256){
    int c = ei[N_EDGES + e];
    if (c / SLICE_W == slice){
      int r = ei[e];
      int pos = atomicAdd(&cnt[c], 1);
      srcb[(c << 6) + pos] = r;
    }
  }
}

// merged: make_dis + graph_starts + w3_to_bf16 (one launch)
__global__ __launch_bounds__(256) void prep(
    const int* __restrict__ cnt, float* __restrict__ dis,
    const int* __restrict__ batch, int* __restrict__ gs,
    const float* __restrict__ w0, const float* __restrict__ w1,
    const float* __restrict__ w2, unsigned int* __restrict__ o0,
    unsigned int* __restrict__ o1, unsigned int* __restrict__ o2){
  int b = blockIdx.x, tid = threadIdx.x;
  if (b < 196){
    int i = b*256 + tid;
    if (i < N_NODES){
      dis[i] = 1.0f / sqrtf((float)(cnt[i] + 1));
      int bb = batch[i];
      int bp = (i == 0) ? -1 : batch[i-1];
      for (int g = bp + 1; g <= bb; ++g) gs[g] = i;
      if (i == N_NODES - 1)
        for (int g = bb + 1; g <= N_GRAPHS; ++g) gs[g] = N_NODES;
    }
  } else {
    int i = (b - 196)*256 + tid;      // 0..24575 (3*8192)
    if (i < 3*8192){
      int a = i >> 13, j = i & 8191;
      const float* src = (a == 0) ? w0 : (a == 1) ? w1 : w2;
      unsigned int* dst = (a == 0) ? o0 : (a == 1) ? o1 : o2;
      float2 v = ((const float2*)src)[j];
      dst[j] = (unsigned int)f2bf(v.x) | ((unsigned int)f2bf(v.y) << 16);
    }
  }
}

// MFMA GEMM: C[i][o] = bf16( sum_k A[i][k]*W[o][k] + bias[o] )
// F32IN: A is f32 (layer 0, converted in-register with identical RNE)
template<bool F32IN>
__global__ __launch_bounds__(256, 2) void gemm_mfma(
    const void* __restrict__ Ain, const unsigned short* __restrict__ Wb,
    const float* __restrict__ bias, unsigned short* __restrict__ C,
    int total_waves){
  int tid = threadIdx.x;
  int lane = tid & 63;
  int wid = blockIdx.x*4 + (tid >> 6);
  int l15 = lane & 15, l4 = lane >> 4;
  bf16x8 wf[8][4];
  #pragma unroll
  for (int ob = 0; ob < 8; ++ob)
    #pragma unroll
    for (int ks = 0; ks < 4; ++ks)
      wf[ob][ks] = *(const bf16x8*)&Wb[(ob*16 + l15)*128 + ks*32 + l4*8];
  float bv[8];
  #pragma unroll
  for (int ob = 0; ob < 8; ++ob) bv[ob] = bias[ob*16 + l15];

  for (int t = wid; t < N_NODES/16; t += total_waves){
    int row0 = t*16;
    bf16x8 af[4];
    #pragma unroll
    for (int ks = 0; ks < 4; ++ks){
      if constexpr (F32IN){
        const float* A = (const float*)Ain;
        const float4* ap = (const float4*)&A[(size_t)(row0 + l15)*128 + ks*32 + l4*8];
        float4 fa = ap[0], fb = ap[1];
        bf16x8 v;
        v[0]=(short)f2bf(fa.x); v[1]=(short)f2bf(fa.y);
        v[2]=(short)f2bf(fa.z); v[3]=(short)f2bf(fa.w);
        v[4]=(short)f2bf(fb.x); v[5]=(short)f2bf(fb.y);
        v[6]=(short)f2bf(fb.z); v[7]=(short)f2bf(fb.w);
        af[ks] = v;
      } else {
        const unsigned short* A = (const unsigned short*)Ain;
        af[ks] = *(const bf16x8*)&A[(size_t)(row0 + l15)*128 + ks*32 + l4*8];
      }
    }
    f32x4 acc[8];
    #pragma unroll
    for (int ob = 0; ob < 8; ++ob) acc[ob] = (f32x4){0.f,0.f,0.f,0.f};
    #pragma unroll
    for (int ks = 0; ks < 4; ++ks)
      #pragma unroll
      for (int ob = 0; ob < 8; ++ob)
        acc[ob] = __builtin_amdgcn_mfma_f32_16x16x32_bf16(af[ks], wf[ob][ks],
                                                          acc[ob], 0, 0, 0);
    #pragma unroll
    for (int ob = 0; ob < 8; ++ob)
      #pragma unroll
      for (int r = 0; r < 4; ++r)
        C[(size_t)(row0 + l4*4 + r)*128 + ob*16 + l15] = f2bf(acc[ob][r] + bv[ob]);
  }
}

// 2 waves per node-quad (edge parity split), 16 lanes/node, uint4 gathers.
// grid = N_NODES/8 blocks of 256.
__global__ __launch_bounds__(256) void aggregate_bf(
    const uint4* __restrict__ xw4,
    const int* __restrict__ cnt, const int* __restrict__ srcb,
    const float* __restrict__ dis,
    uint4* __restrict__ xout4, const float* __restrict__ gw,
    const float* __restrict__ gb, float* __restrict__ gate){
  int tid  = threadIdx.x;
  int lane = tid & 63;
  int wv   = tid >> 6;        // 0..3
  int quad = wv >> 1;         // 0..1
  int par  = wv & 1;          // edge-parity
  int sub  = lane >> 4, l16 = lane & 15;
  int node = blockIdx.x*8 + quad*4 + sub;
  float d  = dis[node];
  int   n  = cnt[node];
  int base = node << 6;
  float acc[8];
  if (par == 0){
    uint4 v = xw4[node*16 + l16];
    float dd = d*d;
    float2 a0 = up2(v.x), a1 = up2(v.y), a2 = up2(v.z), a3 = up2(v.w);
    acc[0]=dd*a0.x; acc[1]=dd*a0.y; acc[2]=dd*a1.x; acc[3]=dd*a1.y;
    acc[4]=dd*a2.x; acc[5]=dd*a2.y; acc[6]=dd*a3.x; acc[7]=dd*a3.y;
  } else {
    #pragma unroll
    for (int i = 0; i < 8; ++i) acc[i] = 0.f;
  }
  int nmax = n;
  nmax = max(nmax, __shfl_xor(nmax, 16, 64));
  nmax = max(nmax, __shfl_xor(nmax, 32, 64));
  for (int e = par*4; e < nmax; e += 8){
    int r0, r1, r2, r3;
    float w0, w1, w2, w3;
    {
      bool v0 = e   < n, v1 = e+1 < n, v2 = e+2 < n, v3 = e+3 < n;
      int  s0 = srcb[base+e], s1 = srcb[base+e+1],
           s2 = srcb[base+e+2], s3 = srcb[base+e+3];
      r0 = v0 ? s0 : node;  r1 = v1 ? s1 : node;
      r2 = v2 ? s2 : node;  r3 = v3 ? s3 : node;
      w0 = v0 ? dis[r0]*d : 0.f;  w1 = v1 ? dis[r1]*d : 0.f;
      w2 = v2 ? dis[r2]*d : 0.f;  w3 = v3 ? dis[r3]*d : 0.f;
    }
    uint4 u0 = xw4[r0*16 + l16];
    uint4 u1 = xw4[r1*16 + l16];
    uint4 u2 = xw4[r2*16 + l16];
    uint4 u3 = xw4[r3*16 + l16];
    {
      float2 b0=up2(u0.x), b1=up2(u0.y), b2=up2(u0.z), b3=up2(u0.w);
      acc[0]+=w0*b0.x; acc[1]+=w0*b0.y; acc[2]+=w0*b1.x; acc[3]+=w0*b1.y;
      acc[4]+=w0*b2.x; acc[5]+=w0*b2.y; acc[6]+=w0*b3.x; acc[7]+=w0*b3.y;
    }
    {
      float2 b0=up2(u1.x), b1=up2(u1.y), b2=up2(u1.z), b3=up2(u1.w);
      acc[0]+=w1*b0.x; acc[1]+=w1*b0.y; acc[2]+=w1*b1.x; acc[3]+=w1*b1.y;
      acc[4]+=w1*b2.x; acc[5]+=w1*b2.y; acc[6]+=w1*b3.x; acc[7]+=w1*b3.y;
    }
    {
      float2 b0=up2(u2.x), b1=up2(u2.y), b2=up2(u2.z), b3=up2(u2.w);
      acc[0]+=w2*b0.x; acc[1]+=w2*b0.y; acc[2]+=w2*b1.x; acc[3]+=w2*b1.y;
      acc[4]+=w2*b2.x; acc[5]+=w2*b2.y; acc[6]+=w2*b3.x; acc[7]+=w2*b3.y;
    }
    {
      float2 b0=up2(u3.x), b1=up2(u3.y), b2=up2(u3.z), b3=up2(u3.w);
      acc[0]+=w3*b0.x; acc[1]+=w3*b0.y; acc[2]+=w3*b1.x; acc[3]+=w3*b1.y;
      acc[4]+=w3*b2.x; acc[5]+=w3*b2.y; acc[6]+=w3*b3.x; acc[7]+=w3*b3.y;
    }
  }
  __shared__ float comb[2][64][9];    // [quad][lane][8+pad]
  if (par == 1){
    #pragma unroll
    for (int i = 0; i < 8; ++i) comb[quad][lane][i] = acc[i];
  }
  __syncthreads();
  if (par == 0){
    #pragma unroll
    for (int i = 0; i < 8; ++i) acc[i] = fmaxf(acc[i] + comb[quad][lane][i], 0.f);
    uint4 o;
    o.x = (unsigned int)f2bf(acc[0]) | ((unsigned int)f2bf(acc[1]) << 16);
    o.y = (unsigned int)f2bf(acc[2]) | ((unsigned int)f2bf(acc[3]) << 16);
    o.z = (unsigned int)f2bf(acc[4]) | ((unsigned int)f2bf(acc[5]) << 16);
    o.w = (unsigned int)f2bf(acc[6]) | ((unsigned int)f2bf(acc[7]) << 16);
    xout4[node*16 + l16] = o;
    const float4* gw4 = (const float4*)gw;
    float4 g0 = gw4[l16*2], g1 = gw4[l16*2 + 1];
    float p = acc[0]*g0.x + acc[1]*g0.y + acc[2]*g0.z + acc[3]*g0.w
            + acc[4]*g1.x + acc[5]*g1.y + acc[6]*g1.z + acc[7]*g1.w;
    p += __shfl_xor(p, 1, 64);
    p += __shfl_xor(p, 2, 64);
    p += __shfl_xor(p, 4, 64);
    p += __shfl_xor(p, 8, 64);
    if (l16 == 0) gate[node] = p + gb[0];
  }
}

// 4 blocks per graph: partial softmax-weighted feature sums (deterministic split)
__global__ __launch_bounds__(256) void att_pool_part(
    const unsigned short* __restrict__ x, const float* __restrict__ gate,
    const int* __restrict__ gs, float* __restrict__ hgp,
    float* __restrict__ ssum){
  int g = blockIdx.x >> 2, q = blockIdx.x & 3, tid = threadIdx.x;
  int s = gs[g], e = gs[g+1];
  __shared__ float red[256];
  float m = -FLT_MAX;
  for (int i = s + tid; i < e; i += 256) m = fmaxf(m, gate[i]);
  red[tid] = m; __syncthreads();
  for (int st = 128; st > 0; st >>= 1){
    if (tid < st) red[tid] = fmaxf(red[tid], red[tid+st]);
    __syncthreads();
  }
  m = red[0]; __syncthreads();
  float p = 0.f;
  for (int i = s + tid; i < e; i += 256) p += __expf(gate[i] - m);
  red[tid] = p; __syncthreads();
  for (int st = 128; st > 0; st >>= 1){
    if (tid < st) red[tid] += red[tid+st];
    __syncthreads();
  }
  if (tid == 0 && q == 0) ssum[g] = red[0];
  __syncthreads();
  int dim = tid & 127, half = tid >> 7;
  float acc = 0.f;
  for (int i = s + q*2 + half; i < e; i += 8)
    acc += __expf(gate[i] - m) * bf2f(x[(size_t)i*128 + dim]);
  red[tid] = acc; __syncthreads();
  if (tid < 128) hgp[(size_t)blockIdx.x*128 + tid] = red[tid] + red[tid+128];
}

// fused: hg[g] = sum_L (sum_q hgp[L][4g+q]) / ssum[L][g]; then 2-layer MLP head
__global__ __launch_bounds__(256) void head(const float* __restrict__ hgp,
    const float* __restrict__ ssum,
    const float* __restrict__ lw, const float* __restrict__ lb,
    const float* __restrict__ cw, const float* __restrict__ cb,
    float* __restrict__ out){
  int g = blockIdx.x, tid = threadIdx.x;
  __shared__ float h[128];
  __shared__ float t1[256];
  __shared__ float red[256];
  if (tid < 128){
    float hv = 0.f;
    #pragma unroll
    for (int L = 0; L < 3; ++L){
      const float* hb = hgp + (size_t)(L*4*N_GRAPHS + 4*g)*128;
      float p = hb[tid] + hb[128 + tid] + hb[256 + tid] + hb[384 + tid];
      float sv = ssum[L*N_GRAPHS + g];
      hv += (sv > 0.f) ? p/sv : 0.f;
    }
    h[tid] = hv;
  }
  __syncthreads();
  const float* wr = lw + tid*128;
  float a = 0.f;
  for (int k = 0; k < 128; ++k) a += h[k]*wr[k];
  a = fmaxf(a + lb[tid], 0.f);
  t1[tid] = a;
  __syncthreads();
  int o = tid >> 7, j = tid & 127;
  float p = t1[j]*cw[o*256 + j] + t1[j+128]*cw[o*256 + j + 128];
  red[tid] = p; __syncthreads();
  for (int st = 64; st > 0; st >>= 1){
    if (j < st) red[tid] += red[tid+st];
    __syncthreads();
  }
  if (j == 0) out[g*2 + o] = red[tid] + cb[o];
}

extern "C" void kernel_launch(void* const* d_in, const int* in_sizes, int n_in,
                              void* d_out, int out_size, void* d_ws, size_t ws_size,
                              hipStream_t stream){
  const float* x   = (const float*)d_in[0];
  const int*   ei  = (const int*)d_in[1];
  const int* batch = (const int*)d_in[2];
  const float* w0  = (const float*)d_in[3];
  const float* b0  = (const float*)d_in[4];
  const float* w1  = (const float*)d_in[5];
  const float* b1  = (const float*)d_in[6];
  const float* w2  = (const float*)d_in[7];
  const float* b2  = (const float*)d_in[8];
  const float* gw  = (const float*)d_in[9];
  const float* gb  = (const float*)d_in[10];
  const float* lw  = (const float*)d_in[11];
  const float* lb  = (const float*)d_in[12];
  const float* cw  = (const float*)d_in[13];
  const float* cb  = (const float*)d_in[14];
  float* out = (float*)d_out;
  (void)in_sizes; (void)n_in; (void)out_size; (void)ws_size;

  char* ws = (char*)d_ws;
  size_t off = 0;
  auto alloc = [&](size_t bytes)->char*{
    char* p = ws + off;
    off = (off + bytes + 255) & ~(size_t)255;
    return p;
  };
  float* dis    = (float*)alloc((size_t)N_NODES*4);
  unsigned int* xw   = (unsigned int*)alloc((size_t)N_NODES*64*4);  // bf16 xw
  unsigned int* xbuf = (unsigned int*)alloc((size_t)N_NODES*64*4);  // bf16 agg out
  unsigned int* Wb0  = (unsigned int*)alloc((size_t)DIM*64*4);
  unsigned int* Wb1  = (unsigned int*)alloc((size_t)DIM*64*4);
  unsigned int* Wb2  = (unsigned int*)alloc((size_t)DIM*64*4);
  float* gate  = (float*)alloc((size_t)N_NODES*4);
  float* hgp   = (float*)alloc((size_t)3*4*N_GRAPHS*DIM*4);
  float* ssum  = (float*)alloc((size_t)3*N_GRAPHS*4);
  int*   gs    = (int*)alloc((size_t)(N_GRAPHS+1)*4);
  int*   cnt   = (int*)alloc((size_t)N_NODES*4);
  int*   srcb  = (int*)alloc(((size_t)N_NODES*CAP + 64)*4);

  const int T = 256;
  zero_i32      <<<(N_NODES+T-1)/T, T, 0, stream>>>(cnt, N_NODES);
  scatter_sliced<<<NCHUNK*NSLICE, T, 0, stream>>>(ei, cnt, srcb);
  prep          <<<196 + 96, T, 0, stream>>>(cnt, dis, batch, gs,
                                             w0, w1, w2, Wb0, Wb1, Wb2);

  const unsigned int* Ws[3] = {Wb0, Wb1, Wb2};
  const float* Bs[3] = {b0, b1, b2};
  const void* xin = (const void*)x;
  const int GEMM_BLKS = 512;           // 2048 waves
  for (int L = 0; L < 3; ++L){
    if (L == 0)
      gemm_mfma<true><<<GEMM_BLKS, 256, 0, stream>>>(
          xin, (const unsigned short*)Ws[L], Bs[L],
          (unsigned short*)xw, GEMM_BLKS*4);
    else
      gemm_mfma<false><<<GEMM_BLKS, 256, 0, stream>>>(
          xin, (const unsigned short*)Ws[L], Bs[L],
          (unsigned short*)xw, GEMM_BLKS*4);
    aggregate_bf<<<N_NODES/8, 256, 0, stream>>>((const uint4*)xw, cnt, srcb,
                                                dis, (uint4*)xbuf, gw, gb, gate);
    att_pool_part<<<4*N_GRAPHS, 256, 0, stream>>>((const unsigned short*)xbuf,
                                                  gate, gs,
                                                  hgp + (size_t)L*4*N_GRAPHS*DIM,
                                                  ssum + (size_t)L*N_GRAPHS);
    xin = (const void*)xbuf;
  }
  head<<<N_GRAPHS, 256, 0, stream>>>(hgp, ssum, lw, lb, cw, cb, out);
}

// Round 10
// 202.326 us; speedup vs baseline: 3.7731x; 1.2274x over previous
//
#include <hip/hip_runtime.h>
#include <hip/hip_bf16.h>
#include <float.h>

#define N_NODES  50000
#define N_EDGES  640000
#define N_GRAPHS 128
#define DIM      128
#define CAP      64    // bucket slots per node; P(deg>=64) ~ 1e-24 per node
#define ZROW     N_NODES   // index of the all-zero row in xw/xbuf
#define NSLICE   8
#define SLICE_W  6250
#define NCHUNK   256
#define CHUNK_E  2500

typedef __attribute__((ext_vector_type(8))) short bf16x8;
typedef __attribute__((ext_vector_type(4))) float f32x4;

__device__ __forceinline__ unsigned short f2bf(float f){
  unsigned int u = __float_as_uint(f);
  u += 0x7fffu + ((u >> 16) & 1u);     // round-to-nearest-even
  return (unsigned short)(u >> 16);
}
__device__ __forceinline__ float bf2f(unsigned short h){
  return __uint_as_float(((unsigned int)h) << 16);
}
__device__ __forceinline__ float2 up2(unsigned int p){
  return make_float2(__uint_as_float(p << 16),
                     __uint_as_float(p & 0xffff0000u));
}

// zero cnt + the two zero-rows (xw, xbuf)
__global__ __launch_bounds__(256) void zero_misc(int* __restrict__ cnt,
    unsigned int* __restrict__ z0, unsigned int* __restrict__ z1){
  int i = blockIdx.x*256 + threadIdx.x;
  if (i < N_NODES) cnt[i] = 0;
  else if (i < N_NODES + 64) z0[i - N_NODES] = 0;
  else if (i < N_NODES + 128) z1[i - N_NODES - 64] = 0;
}

// XCD-sliced scatter (L2-locality heuristic only; correctness order-free)
__global__ __launch_bounds__(256) void scatter_sliced(
    const int* __restrict__ ei, int* __restrict__ cnt, int* __restrict__ srcb){
  int slice = blockIdx.x & (NSLICE-1);
  int chunk = blockIdx.x >> 3;
  int e0 = chunk * CHUNK_E;
  for (int e = e0 + threadIdx.x; e < e0 + CHUNK_E; e += 256){
    int c = ei[N_EDGES + e];
    if (c / SLICE_W == slice){
      int r = ei[e];
      int pos = atomicAdd(&cnt[c], 1);
      srcb[(c << 6) + pos] = r;
    }
  }
}

// merged: make_dis + graph_starts + w3_to_bf16
__global__ __launch_bounds__(256) void prep(
    const int* __restrict__ cnt, float* __restrict__ dis,
    const int* __restrict__ batch, int* __restrict__ gs,
    const float* __restrict__ w0, const float* __restrict__ w1,
    const float* __restrict__ w2, unsigned int* __restrict__ o0,
    unsigned int* __restrict__ o1, unsigned int* __restrict__ o2){
  int b = blockIdx.x, tid = threadIdx.x;
  if (b < 196){
    int i = b*256 + tid;
    if (i < N_NODES){
      dis[i] = 1.0f / sqrtf((float)(cnt[i] + 1));
      int bb = batch[i];
      int bp = (i == 0) ? -1 : batch[i-1];
      for (int g = bp + 1; g <= bb; ++g) gs[g] = i;
      if (i == N_NODES - 1)
        for (int g = bb + 1; g <= N_GRAPHS; ++g) gs[g] = N_NODES;
    }
  } else {
    int i = (b - 196)*256 + tid;
    if (i < 3*8192){
      int a = i >> 13, j = i & 8191;
      const float* src = (a == 0) ? w0 : (a == 1) ? w1 : w2;
      unsigned int* dst = (a == 0) ? o0 : (a == 1) ? o1 : o2;
      float2 v = ((const float2*)src)[j];
      dst[j] = (unsigned int)f2bf(v.x) | ((unsigned int)f2bf(v.y) << 16);
    }
  }
}

// MFMA GEMM with dis-scaled epilogue: C[i][o] = bf16( dis[i]*(sum_k A[i][k]*W[o][k] + bias[o]) )
template<bool F32IN>
__global__ __launch_bounds__(256, 2) void gemm_mfma(
    const void* __restrict__ Ain, const unsigned short* __restrict__ Wb,
    const float* __restrict__ bias, const float* __restrict__ dis,
    unsigned short* __restrict__ C, int total_waves){
  int tid = threadIdx.x;
  int lane = tid & 63;
  int wid = blockIdx.x*4 + (tid >> 6);
  int l15 = lane & 15, l4 = lane >> 4;
  bf16x8 wf[8][4];
  #pragma unroll
  for (int ob = 0; ob < 8; ++ob)
    #pragma unroll
    for (int ks = 0; ks < 4; ++ks)
      wf[ob][ks] = *(const bf16x8*)&Wb[(ob*16 + l15)*128 + ks*32 + l4*8];
  float bv[8];
  #pragma unroll
  for (int ob = 0; ob < 8; ++ob) bv[ob] = bias[ob*16 + l15];

  for (int t = wid; t < N_NODES/16; t += total_waves){
    int row0 = t*16;
    bf16x8 af[4];
    #pragma unroll
    for (int ks = 0; ks < 4; ++ks){
      if constexpr (F32IN){
        const float* A = (const float*)Ain;
        const float4* ap = (const float4*)&A[(size_t)(row0 + l15)*128 + ks*32 + l4*8];
        float4 fa = ap[0], fb = ap[1];
        bf16x8 v;
        v[0]=(short)f2bf(fa.x); v[1]=(short)f2bf(fa.y);
        v[2]=(short)f2bf(fa.z); v[3]=(short)f2bf(fa.w);
        v[4]=(short)f2bf(fb.x); v[5]=(short)f2bf(fb.y);
        v[6]=(short)f2bf(fb.z); v[7]=(short)f2bf(fb.w);
        af[ks] = v;
      } else {
        const unsigned short* A = (const unsigned short*)Ain;
        af[ks] = *(const bf16x8*)&A[(size_t)(row0 + l15)*128 + ks*32 + l4*8];
      }
    }
    f32x4 acc[8];
    #pragma unroll
    for (int ob = 0; ob < 8; ++ob) acc[ob] = (f32x4){0.f,0.f,0.f,0.f};
    #pragma unroll
    for (int ks = 0; ks < 4; ++ks)
      #pragma unroll
      for (int ob = 0; ob < 8; ++ob)
        acc[ob] = __builtin_amdgcn_mfma_f32_16x16x32_bf16(af[ks], wf[ob][ks],
                                                          acc[ob], 0, 0, 0);
    float dv[4];
    #pragma unroll
    for (int r = 0; r < 4; ++r) dv[r] = dis[row0 + l4*4 + r];
    #pragma unroll
    for (int ob = 0; ob < 8; ++ob)
      #pragma unroll
      for (int r = 0; r < 4; ++r)
        C[(size_t)(row0 + l4*4 + r)*128 + ob*16 + l15] =
            f2bf((acc[ob][r] + bv[ob]) * dv[r]);
  }
}

// rows pre-scaled by dis[r]: out[c] = relu(dis[c]*(xw_s[c] + sum_in xw_s[r]))
// 2 waves per node-quad (edge parity), 16 lanes/node, 8-deep uint4 gathers.
__global__ __launch_bounds__(256) void aggregate_bf(
    const uint4* __restrict__ xw4,
    const int* __restrict__ cnt, const int* __restrict__ srcb,
    const float* __restrict__ dis,
    uint4* __restrict__ xout4, const float* __restrict__ gw,
    const float* __restrict__ gb, float* __restrict__ gate){
  int tid  = threadIdx.x;
  int lane = tid & 63;
  int wv   = tid >> 6;
  int quad = wv >> 1;
  int par  = wv & 1;
  int sub  = lane >> 4, l16 = lane & 15;
  int node = blockIdx.x*8 + quad*4 + sub;
  int   n  = cnt[node];
  int base = node << 6;
  float acc[8];
  if (par == 0){
    uint4 v = xw4[node*16 + l16];
    float2 a0 = up2(v.x), a1 = up2(v.y), a2 = up2(v.z), a3 = up2(v.w);
    acc[0]=a0.x; acc[1]=a0.y; acc[2]=a1.x; acc[3]=a1.y;
    acc[4]=a2.x; acc[5]=a2.y; acc[6]=a3.x; acc[7]=a3.y;
  } else {
    #pragma unroll
    for (int i = 0; i < 8; ++i) acc[i] = 0.f;
  }
  int nmax = n;
  nmax = max(nmax, __shfl_xor(nmax, 16, 64));
  nmax = max(nmax, __shfl_xor(nmax, 32, 64));
  for (int e = par*8; e < nmax; e += 16){
    int4 sa = *(const int4*)&srcb[base + e];
    int4 sb = *(const int4*)&srcb[base + e + 4];
    int r0 = (e   < n) ? sa.x : ZROW;
    int r1 = (e+1 < n) ? sa.y : ZROW;
    int r2 = (e+2 < n) ? sa.z : ZROW;
    int r3 = (e+3 < n) ? sa.w : ZROW;
    int r4 = (e+4 < n) ? sb.x : ZROW;
    int r5 = (e+5 < n) ? sb.y : ZROW;
    int r6 = (e+6 < n) ? sb.z : ZROW;
    int r7 = (e+7 < n) ? sb.w : ZROW;
    uint4 u0 = xw4[r0*16 + l16];
    uint4 u1 = xw4[r1*16 + l16];
    uint4 u2 = xw4[r2*16 + l16];
    uint4 u3 = xw4[r3*16 + l16];
    uint4 u4 = xw4[r4*16 + l16];
    uint4 u5 = xw4[r5*16 + l16];
    uint4 u6 = xw4[r6*16 + l16];
    uint4 u7 = xw4[r7*16 + l16];
    #define ACC8(U) { \
      float2 b0=up2(U.x), b1=up2(U.y), b2=up2(U.z), b3=up2(U.w); \
      acc[0]+=b0.x; acc[1]+=b0.y; acc[2]+=b1.x; acc[3]+=b1.y;    \
      acc[4]+=b2.x; acc[5]+=b2.y; acc[6]+=b3.x; acc[7]+=b3.y; }
    ACC8(u0) ACC8(u1) ACC8(u2) ACC8(u3)
    ACC8(u4) ACC8(u5) ACC8(u6) ACC8(u7)
    #undef ACC8
  }
  __shared__ float comb[2][64][9];
  if (par == 1){
    #pragma unroll
    for (int i = 0; i < 8; ++i) comb[quad][lane][i] = acc[i];
  }
  __syncthreads();
  if (par == 0){
    float d = dis[node];
    #pragma unroll
    for (int i = 0; i < 8; ++i)
      acc[i] = fmaxf(d*(acc[i] + comb[quad][lane][i]), 0.f);
    uint4 o;
    o.x = (unsigned int)f2bf(acc[0]) | ((unsigned int)f2bf(acc[1]) << 16);
    o.y = (unsigned int)f2bf(acc[2]) | ((unsigned int)f2bf(acc[3]) << 16);
    o.z = (unsigned int)f2bf(acc[4]) | ((unsigned int)f2bf(acc[5]) << 16);
    o.w = (unsigned int)f2bf(acc[6]) | ((unsigned int)f2bf(acc[7]) << 16);
    xout4[node*16 + l16] = o;
    const float4* gw4 = (const float4*)gw;
    float4 g0 = gw4[l16*2], g1 = gw4[l16*2 + 1];
    float p = acc[0]*g0.x + acc[1]*g0.y + acc[2]*g0.z + acc[3]*g0.w
            + acc[4]*g1.x + acc[5]*g1.y + acc[6]*g1.z + acc[7]*g1.w;
    p += __shfl_xor(p, 1, 64);
    p += __shfl_xor(p, 2, 64);
    p += __shfl_xor(p, 4, 64);
    p += __shfl_xor(p, 8, 64);
    if (l16 == 0) gate[node] = p + gb[0];
  }
}

// one block per graph: gate -> normalized alpha (in place)
__global__ __launch_bounds__(256) void gate_reduce(float* __restrict__ gate,
    const int* __restrict__ gs){
  int g = blockIdx.x, tid = threadIdx.x;
  int s = gs[g], e = gs[g+1];
  __shared__ float red[256];
  float m = -FLT_MAX;
  for (int i = s + tid; i < e; i += 256) m = fmaxf(m, gate[i]);
  red[tid] = m; __syncthreads();
  for (int st = 128; st > 0; st >>= 1){
    if (tid < st) red[tid] = fmaxf(red[tid], red[tid+st]);
    __syncthreads();
  }
  m = red[0]; __syncthreads();
  float p = 0.f;
  for (int i = s + tid; i < e; i += 256){
    float ev = __expf(gate[i] - m);
    gate[i] = ev;
    p += ev;
  }
  red[tid] = p; __syncthreads();
  for (int st = 128; st > 0; st >>= 1){
    if (tid < st) red[tid] += red[tid+st];
    __syncthreads();
  }
  float inv = (red[0] > 0.f) ? 1.0f/red[0] : 0.f;
  for (int i = s + tid; i < e; i += 256) gate[i] *= inv;
}

// 8 blocks per graph: pure weighted feature sum (alpha precomputed)
__global__ __launch_bounds__(256) void att_pool_part(
    const unsigned int* __restrict__ x, const float* __restrict__ alpha,
    const int* __restrict__ gs, float* __restrict__ hgp){
  int g = blockIdx.x >> 3, q = blockIdx.x & 7, tid = threadIdx.x;
  int s = gs[g], e = gs[g+1];
  int d2 = tid & 63, rg = tid >> 6;
  float ax = 0.f, ay = 0.f;
  for (int i = s + q*4 + rg; i < e; i += 32){
    float a = alpha[i];
    float2 u = up2(x[(size_t)i*64 + d2]);
    ax += a*u.x; ay += a*u.y;
  }
  __shared__ float2 red[4][64];
  red[rg][d2] = make_float2(ax, ay);
  __syncthreads();
  if (tid < 64){
    float2 r0 = red[0][tid], r1 = red[1][tid], r2 = red[2][tid], r3 = red[3][tid];
    hgp[(size_t)blockIdx.x*128 + 2*tid    ] = r0.x + r1.x + r2.x + r3.x;
    hgp[(size_t)blockIdx.x*128 + 2*tid + 1] = r0.y + r1.y + r2.y + r3.y;
  }
}

// hg[g] = sum_L sum_q hgp[L][8g+q]; then relu(hg@lw.T+lb)@cw.T+cb
__global__ __launch_bounds__(256) void head(const float* __restrict__ hgp,
    const float* __restrict__ lw, const float* __restrict__ lb,
    const float* __restrict__ cw, const float* __restrict__ cb,
    float* __restrict__ out){
  int g = blockIdx.x, tid = threadIdx.x;
  __shared__ float h[128];
  __shared__ float t1[256];
  __shared__ float red[256];
  if (tid < 128){
    float hv = 0.f;
    #pragma unroll
    for (int L = 0; L < 3; ++L){
      const float* hb = hgp + (size_t)(L*8*N_GRAPHS + 8*g)*128;
      #pragma unroll
      for (int q = 0; q < 8; ++q) hv += hb[q*128 + tid];
    }
    h[tid] = hv;
  }
  __syncthreads();
  const float* wr = lw + tid*128;
  float a = 0.f;
  for (int k = 0; k < 128; ++k) a += h[k]*wr[k];
  a = fmaxf(a + lb[tid], 0.f);
  t1[tid] = a;
  __syncthreads();
  int o = tid >> 7, j = tid & 127;
  float p = t1[j]*cw[o*256 + j] + t1[j+128]*cw[o*256 + j + 128];
  red[tid] = p; __syncthreads();
  for (int st = 64; st > 0; st >>= 1){
    if (j < st) red[tid] += red[tid+st];
    __syncthreads();
  }
  if (j == 0) out[g*2 + o] = red[tid] + cb[o];
}

extern "C" void kernel_launch(void* const* d_in, const int* in_sizes, int n_in,
                              void* d_out, int out_size, void* d_ws, size_t ws_size,
                              hipStream_t stream){
  const float* x   = (const float*)d_in[0];
  const int*   ei  = (const int*)d_in[1];
  const int* batch = (const int*)d_in[2];
  const float* w0  = (const float*)d_in[3];
  const float* b0  = (const float*)d_in[4];
  const float* w1  = (const float*)d_in[5];
  const float* b1  = (const float*)d_in[6];
  const float* w2  = (const float*)d_in[7];
  const float* b2  = (const float*)d_in[8];
  const float* gw  = (const float*)d_in[9];
  const float* gb  = (const float*)d_in[10];
  const float* lw  = (const float*)d_in[11];
  const float* lb  = (const float*)d_in[12];
  const float* cw  = (const float*)d_in[13];
  const float* cb  = (const float*)d_in[14];
  float* out = (float*)d_out;
  (void)in_sizes; (void)n_in; (void)out_size; (void)ws_size;

  char* ws = (char*)d_ws;
  size_t off = 0;
  auto alloc = [&](size_t bytes)->char*{
    char* p = ws + off;
    off = (off + bytes + 255) & ~(size_t)255;
    return p;
  };
  float* dis    = (float*)alloc((size_t)N_NODES*4);
  unsigned int* xw   = (unsigned int*)alloc((size_t)(N_NODES+1)*64*4); // +zero row
  unsigned int* xbuf = (unsigned int*)alloc((size_t)(N_NODES+1)*64*4); // +zero row
  unsigned int* Wb0  = (unsigned int*)alloc((size_t)DIM*64*4);
  unsigned int* Wb1  = (unsigned int*)alloc((size_t)DIM*64*4);
  unsigned int* Wb2  = (unsigned int*)alloc((size_t)DIM*64*4);
  float* gate  = (float*)alloc((size_t)N_NODES*4);
  float* hgp   = (float*)alloc((size_t)3*8*N_GRAPHS*DIM*4);
  int*   gs    = (int*)alloc((size_t)(N_GRAPHS+1)*4);
  int*   cnt   = (int*)alloc((size_t)N_NODES*4);
  int*   srcb  = (int*)alloc(((size_t)N_NODES*CAP + 64)*4);

  const int T = 256;
  zero_misc     <<<(N_NODES+128+T-1)/T, T, 0, stream>>>(cnt,
                    xw + (size_t)ZROW*64, xbuf + (size_t)ZROW*64);
  scatter_sliced<<<NCHUNK*NSLICE, T, 0, stream>>>(ei, cnt, srcb);
  prep          <<<196 + 96, T, 0, stream>>>(cnt, dis, batch, gs,
                                             w0, w1, w2, Wb0, Wb1, Wb2);

  const unsigned int* Ws[3] = {Wb0, Wb1, Wb2};
  const float* Bs[3] = {b0, b1, b2};
  const void* xin = (const void*)x;
  const int GEMM_BLKS = 512;           // 2048 waves
  for (int L = 0; L < 3; ++L){
    if (L == 0)
      gemm_mfma<true><<<GEMM_BLKS, 256, 0, stream>>>(
          xin, (const unsigned short*)Ws[L], Bs[L], dis,
          (unsigned short*)xw, GEMM_BLKS*4);
    else
      gemm_mfma<false><<<GEMM_BLKS, 256, 0, stream>>>(
          xin, (const unsigned short*)Ws[L], Bs[L], dis,
          (unsigned short*)xw, GEMM_BLKS*4);
    aggregate_bf<<<N_NODES/8, 256, 0, stream>>>((const uint4*)xw, cnt, srcb,
                                                dis, (uint4*)xbuf, gw, gb, gate);
    gate_reduce <<<N_GRAPHS, 256, 0, stream>>>(gate, gs);
    att_pool_part<<<8*N_GRAPHS, 256, 0, stream>>>(xbuf, gate, gs,
                                                  hgp + (size_t)L*8*N_GRAPHS*DIM);
    xin = (const void*)xbuf;
  }
  head<<<N_GRAPHS, 256, 0, stream>>>(hgp, lw, lb, cw, cb, out);
}

// Round 11
// 198.671 us; speedup vs baseline: 3.8425x; 1.0184x over previous
//
#include <hip/hip_runtime.h>
#include <hip/hip_bf16.h>
#include <float.h>

#define N_NODES  50000
#define N_EDGES  640000
#define N_GRAPHS 128
#define DIM      128
#define CAP      64        // bucket slots per node; P(deg>=64) ~ 1e-24 per node
#define ZROW     N_NODES   // index of the all-zero row in xw/xbuf
#define NSLICE   8
#define SLICE_W  6250
#define NCHUNK   256
#define CHUNK_E  2500
#define GEMM_BLKS 512
#define POOL_BLKS 1024     // 8 per graph
#define AGG_BLKS  (8*782)  // 8 slices x ceil(6250/8)

typedef __attribute__((ext_vector_type(8))) short bf16x8;
typedef __attribute__((ext_vector_type(4))) float f32x4;

__device__ __forceinline__ unsigned short f2bf(float f){
  unsigned int u = __float_as_uint(f);
  u += 0x7fffu + ((u >> 16) & 1u);     // round-to-nearest-even
  return (unsigned short)(u >> 16);
}
__device__ __forceinline__ float2 up2(unsigned int p){
  return make_float2(__uint_as_float(p << 16),
                     __uint_as_float(p & 0xffff0000u));
}

// zero cnt + the two zero-rows (xw, xbuf)
__global__ __launch_bounds__(256) void zero_misc(int* __restrict__ cnt,
    unsigned int* __restrict__ z0, unsigned int* __restrict__ z1){
  int i = blockIdx.x*256 + threadIdx.x;
  if (i < N_NODES) cnt[i] = 0;
  else if (i < N_NODES + 64) z0[i - N_NODES] = 0;
  else if (i < N_NODES + 128) z1[i - N_NODES - 64] = 0;
}

// XCD-sliced scatter (L2-locality heuristic only; correctness order-free)
__global__ __launch_bounds__(256) void scatter_sliced(
    const int* __restrict__ ei, int* __restrict__ cnt, int* __restrict__ srcb){
  int slice = blockIdx.x & (NSLICE-1);
  int chunk = blockIdx.x >> 3;
  int e0 = chunk * CHUNK_E;
  for (int e = e0 + threadIdx.x; e < e0 + CHUNK_E; e += 256){
    int c = ei[N_EDGES + e];
    if (c / SLICE_W == slice){
      int r = ei[e];
      int pos = atomicAdd(&cnt[c], 1);
      srcb[(c << 6) + pos] = r;
    }
  }
}

// merged: make_dis + graph_starts + w3_to_bf16
__global__ __launch_bounds__(256) void prep(
    const int* __restrict__ cnt, float* __restrict__ dis,
    const int* __restrict__ batch, int* __restrict__ gs,
    const float* __restrict__ w0, const float* __restrict__ w1,
    const float* __restrict__ w2, unsigned int* __restrict__ o0,
    unsigned int* __restrict__ o1, unsigned int* __restrict__ o2){
  int b = blockIdx.x, tid = threadIdx.x;
  if (b < 196){
    int i = b*256 + tid;
    if (i < N_NODES){
      dis[i] = 1.0f / sqrtf((float)(cnt[i] + 1));
      int bb = batch[i];
      int bp = (i == 0) ? -1 : batch[i-1];
      for (int g = bp + 1; g <= bb; ++g) gs[g] = i;
      if (i == N_NODES - 1)
        for (int g = bb + 1; g <= N_GRAPHS; ++g) gs[g] = N_NODES;
    }
  } else {
    int i = (b - 196)*256 + tid;
    if (i < 3*8192){
      int a = i >> 13, j = i & 8191;
      const float* src = (a == 0) ? w0 : (a == 1) ? w1 : w2;
      unsigned int* dst = (a == 0) ? o0 : (a == 1) ? o1 : o2;
      float2 v = ((const float2*)src)[j];
      dst[j] = (unsigned int)f2bf(v.x) | ((unsigned int)f2bf(v.y) << 16);
    }
  }
}

// ---- GEMM body (bf16 input), dis-scaled epilogue ----
__device__ __forceinline__ void gemm_body_bf(int wid,
    const unsigned short* __restrict__ A, const unsigned short* __restrict__ Wb,
    const float* __restrict__ bias, const float* __restrict__ dis,
    unsigned short* __restrict__ C, int total_waves){
  int lane = threadIdx.x & 63;
  int l15 = lane & 15, l4 = lane >> 4;
  bf16x8 wf[8][4];
  #pragma unroll
  for (int ob = 0; ob < 8; ++ob)
    #pragma unroll
    for (int ks = 0; ks < 4; ++ks)
      wf[ob][ks] = *(const bf16x8*)&Wb[(ob*16 + l15)*128 + ks*32 + l4*8];
  float bv[8];
  #pragma unroll
  for (int ob = 0; ob < 8; ++ob) bv[ob] = bias[ob*16 + l15];
  for (int t = wid; t < N_NODES/16; t += total_waves){
    int row0 = t*16;
    bf16x8 af[4];
    #pragma unroll
    for (int ks = 0; ks < 4; ++ks)
      af[ks] = *(const bf16x8*)&A[(size_t)(row0 + l15)*128 + ks*32 + l4*8];
    f32x4 acc[8];
    #pragma unroll
    for (int ob = 0; ob < 8; ++ob) acc[ob] = (f32x4){0.f,0.f,0.f,0.f};
    #pragma unroll
    for (int ks = 0; ks < 4; ++ks)
      #pragma unroll
      for (int ob = 0; ob < 8; ++ob)
        acc[ob] = __builtin_amdgcn_mfma_f32_16x16x32_bf16(af[ks], wf[ob][ks],
                                                          acc[ob], 0, 0, 0);
    float dv[4];
    #pragma unroll
    for (int r = 0; r < 4; ++r) dv[r] = dis[row0 + l4*4 + r];
    #pragma unroll
    for (int ob = 0; ob < 8; ++ob)
      #pragma unroll
      for (int r = 0; r < 4; ++r)
        C[(size_t)(row0 + l4*4 + r)*128 + ob*16 + l15] =
            f2bf((acc[ob][r] + bv[ob]) * dv[r]);
  }
}

// layer-0 GEMM: f32 input, in-register RNE to bf16
__global__ __launch_bounds__(256, 2) void gemm_f32(
    const float* __restrict__ A, const unsigned short* __restrict__ Wb,
    const float* __restrict__ bias, const float* __restrict__ dis,
    unsigned short* __restrict__ C, int total_waves){
  int lane = threadIdx.x & 63;
  int wid = blockIdx.x*4 + (threadIdx.x >> 6);
  int l15 = lane & 15, l4 = lane >> 4;
  bf16x8 wf[8][4];
  #pragma unroll
  for (int ob = 0; ob < 8; ++ob)
    #pragma unroll
    for (int ks = 0; ks < 4; ++ks)
      wf[ob][ks] = *(const bf16x8*)&Wb[(ob*16 + l15)*128 + ks*32 + l4*8];
  float bv[8];
  #pragma unroll
  for (int ob = 0; ob < 8; ++ob) bv[ob] = bias[ob*16 + l15];
  for (int t = wid; t < N_NODES/16; t += total_waves){
    int row0 = t*16;
    bf16x8 af[4];
    #pragma unroll
    for (int ks = 0; ks < 4; ++ks){
      const float4* ap = (const float4*)&A[(size_t)(row0 + l15)*128 + ks*32 + l4*8];
      float4 fa = ap[0], fb = ap[1];
      bf16x8 v;
      v[0]=(short)f2bf(fa.x); v[1]=(short)f2bf(fa.y);
      v[2]=(short)f2bf(fa.z); v[3]=(short)f2bf(fa.w);
      v[4]=(short)f2bf(fb.x); v[5]=(short)f2bf(fb.y);
      v[6]=(short)f2bf(fb.z); v[7]=(short)f2bf(fb.w);
      af[ks] = v;
    }
    f32x4 acc[8];
    #pragma unroll
    for (int ob = 0; ob < 8; ++ob) acc[ob] = (f32x4){0.f,0.f,0.f,0.f};
    #pragma unroll
    for (int ks = 0; ks < 4; ++ks)
      #pragma unroll
      for (int ob = 0; ob < 8; ++ob)
        acc[ob] = __builtin_amdgcn_mfma_f32_16x16x32_bf16(af[ks], wf[ob][ks],
                                                          acc[ob], 0, 0, 0);
    float dv[4];
    #pragma unroll
    for (int r = 0; r < 4; ++r) dv[r] = dis[row0 + l4*4 + r];
    #pragma unroll
    for (int ob = 0; ob < 8; ++ob)
      #pragma unroll
      for (int r = 0; r < 4; ++r)
        C[(size_t)(row0 + l4*4 + r)*128 + ob*16 + l15] =
            f2bf((acc[ob][r] + bv[ob]) * dv[r]);
  }
}

// ---- pooling body: redundant per-block max/sum; q==0 writes ssum ----
__device__ __forceinline__ void pool_body(int pbid,
    const unsigned int* __restrict__ x, const float* __restrict__ gate,
    const int* __restrict__ gs, float* __restrict__ hgp,
    float* __restrict__ ssum){
  int g = pbid >> 3, q = pbid & 7, tid = threadIdx.x;
  int s = gs[g], e = gs[g+1];
  __shared__ float red[256];
  __shared__ float2 red2[4][64];
  float m = -FLT_MAX;
  for (int i = s + tid; i < e; i += 256) m = fmaxf(m, gate[i]);
  red[tid] = m; __syncthreads();
  for (int st = 128; st > 0; st >>= 1){
    if (tid < st) red[tid] = fmaxf(red[tid], red[tid+st]);
    __syncthreads();
  }
  m = red[0]; __syncthreads();
  float p = 0.f;
  for (int i = s + tid; i < e; i += 256) p += __expf(gate[i] - m);
  red[tid] = p; __syncthreads();
  for (int st = 128; st > 0; st >>= 1){
    if (tid < st) red[tid] += red[tid+st];
    __syncthreads();
  }
  if (tid == 0 && q == 0) ssum[g] = red[0];
  int d2 = tid & 63, rg = tid >> 6;
  float ax = 0.f, ay = 0.f;
  for (int i = s + q*4 + rg; i < e; i += 32){
    float a = __expf(gate[i] - m);
    float2 u = up2(x[(size_t)i*64 + d2]);
    ax += a*u.x; ay += a*u.y;
  }
  red2[rg][d2] = make_float2(ax, ay);
  __syncthreads();
  if (tid < 64){
    float2 r0 = red2[0][tid], r1 = red2[1][tid],
           r2 = red2[2][tid], r3 = red2[3][tid];
    hgp[(size_t)pbid*128 + 2*tid    ] = r0.x + r1.x + r2.x + r3.x;
    hgp[(size_t)pbid*128 + 2*tid + 1] = r0.y + r1.y + r2.y + r3.y;
  }
}

// fused: blocks [0,GEMM_BLKS) = next-layer GEMM; rest = this-layer pooling.
// Both only READ xb; outputs disjoint (xwout vs hgp/ssum). No sync needed.
__global__ __launch_bounds__(256, 2) void pool_gemm(
    const unsigned int* __restrict__ xb, const float* __restrict__ gate,
    const int* __restrict__ gs, float* __restrict__ hgp,
    float* __restrict__ ssum,
    const unsigned short* __restrict__ Wb, const float* __restrict__ bias,
    const float* __restrict__ dis, unsigned short* __restrict__ xwout){
  if (blockIdx.x < GEMM_BLKS){
    int wid = blockIdx.x*4 + (threadIdx.x >> 6);
    gemm_body_bf(wid, (const unsigned short*)xb, Wb, bias, dis, xwout,
                 GEMM_BLKS*4);
  } else {
    pool_body(blockIdx.x - GEMM_BLKS, xb, gate, gs, hgp, ssum);
  }
}

// standalone pooling (last layer)
__global__ __launch_bounds__(256) void att_pool(
    const unsigned int* __restrict__ xb, const float* __restrict__ gate,
    const int* __restrict__ gs, float* __restrict__ hgp,
    float* __restrict__ ssum){
  pool_body(blockIdx.x, xb, gate, gs, hgp, ssum);
}

// rows pre-scaled by dis[r]: out[c] = relu(dis[c]*(xw_s[c] + sum_in xw_s[r]))
// XCD-aligned node mapping; per-group loop bound (exec-masked tails).
__global__ __launch_bounds__(256) void aggregate_bf(
    const uint4* __restrict__ xw4,
    const int* __restrict__ cnt, const int* __restrict__ srcb,
    const float* __restrict__ dis,
    uint4* __restrict__ xout4, const float* __restrict__ gw,
    const float* __restrict__ gb, float* __restrict__ gate){
  int tid  = threadIdx.x;
  int lane = tid & 63;
  int wv   = tid >> 6;
  int quad = wv >> 1;
  int par  = wv & 1;
  int sub  = lane >> 4, l16 = lane & 15;
  int slice = blockIdx.x & 7, within = blockIdx.x >> 3;
  int loc   = within*8 + quad*4 + sub;
  bool valid = loc < SLICE_W;
  int node  = slice*SLICE_W + (valid ? loc : SLICE_W-1);
  int n     = valid ? cnt[node] : 0;
  int base  = node << 6;
  float acc[8];
  #pragma unroll
  for (int i = 0; i < 8; ++i) acc[i] = 0.f;
  if (par == 0 && valid){
    uint4 v = xw4[node*16 + l16];
    float2 a0 = up2(v.x), a1 = up2(v.y), a2 = up2(v.z), a3 = up2(v.w);
    acc[0]=a0.x; acc[1]=a0.y; acc[2]=a1.x; acc[3]=a1.y;
    acc[4]=a2.x; acc[5]=a2.y; acc[6]=a3.x; acc[7]=a3.y;
  }
  for (int e = par*8; e < n; e += 16){
    int4 sa = *(const int4*)&srcb[base + e];
    int4 sb = *(const int4*)&srcb[base + e + 4];
    int r0 = (e   < n) ? sa.x : ZROW;
    int r1 = (e+1 < n) ? sa.y : ZROW;
    int r2 = (e+2 < n) ? sa.z : ZROW;
    int r3 = (e+3 < n) ? sa.w : ZROW;
    int r4 = (e+4 < n) ? sb.x : ZROW;
    int r5 = (e+5 < n) ? sb.y : ZROW;
    int r6 = (e+6 < n) ? sb.z : ZROW;
    int r7 = (e+7 < n) ? sb.w : ZROW;
    uint4 u0 = xw4[r0*16 + l16];
    uint4 u1 = xw4[r1*16 + l16];
    uint4 u2 = xw4[r2*16 + l16];
    uint4 u3 = xw4[r3*16 + l16];
    uint4 u4 = xw4[r4*16 + l16];
    uint4 u5 = xw4[r5*16 + l16];
    uint4 u6 = xw4[r6*16 + l16];
    uint4 u7 = xw4[r7*16 + l16];
    #define ACC8(U) { \
      float2 b0=up2(U.x), b1=up2(U.y), b2=up2(U.z), b3=up2(U.w); \
      acc[0]+=b0.x; acc[1]+=b0.y; acc[2]+=b1.x; acc[3]+=b1.y;    \
      acc[4]+=b2.x; acc[5]+=b2.y; acc[6]+=b3.x; acc[7]+=b3.y; }
    ACC8(u0) ACC8(u1) ACC8(u2) ACC8(u3)
    ACC8(u4) ACC8(u5) ACC8(u6) ACC8(u7)
    #undef ACC8
  }
  __shared__ float comb[2][64][9];
  if (par == 1){
    #pragma unroll
    for (int i = 0; i < 8; ++i) comb[quad][lane][i] = acc[i];
  }
  __syncthreads();
  if (par == 0 && valid){
    float d = dis[node];
    #pragma unroll
    for (int i = 0; i < 8; ++i)
      acc[i] = fmaxf(d*(acc[i] + comb[quad][lane][i]), 0.f);
    uint4 o;
    o.x = (unsigned int)f2bf(acc[0]) | ((unsigned int)f2bf(acc[1]) << 16);
    o.y = (unsigned int)f2bf(acc[2]) | ((unsigned int)f2bf(acc[3]) << 16);
    o.z = (unsigned int)f2bf(acc[4]) | ((unsigned int)f2bf(acc[5]) << 16);
    o.w = (unsigned int)f2bf(acc[6]) | ((unsigned int)f2bf(acc[7]) << 16);
    xout4[node*16 + l16] = o;
    const float4* gw4 = (const float4*)gw;
    float4 g0 = gw4[l16*2], g1 = gw4[l16*2 + 1];
    float p = acc[0]*g0.x + acc[1]*g0.y + acc[2]*g0.z + acc[3]*g0.w
            + acc[4]*g1.x + acc[5]*g1.y + acc[6]*g1.z + acc[7]*g1.w;
    p += __shfl_xor(p, 1, 64);
    p += __shfl_xor(p, 2, 64);
    p += __shfl_xor(p, 4, 64);
    p += __shfl_xor(p, 8, 64);
    if (l16 == 0) gate[node] = p + gb[0];
  }
}

// hg[g] = sum_L (sum_q hgp[L][8g+q]) / ssum[L][g]; then MLP head
__global__ __launch_bounds__(256) void head(const float* __restrict__ hgp,
    const float* __restrict__ ssum,
    const float* __restrict__ lw, const float* __restrict__ lb,
    const float* __restrict__ cw, const float* __restrict__ cb,
    float* __restrict__ out){
  int g = blockIdx.x, tid = threadIdx.x;
  __shared__ float h[128];
  __shared__ float t1[256];
  __shared__ float red[256];
  if (tid < 128){
    float hv = 0.f;
    #pragma unroll
    for (int L = 0; L < 3; ++L){
      const float* hb = hgp + (size_t)(L*POOL_BLKS + 8*g)*128;
      float pp = 0.f;
      #pragma unroll
      for (int q = 0; q < 8; ++q) pp += hb[q*128 + tid];
      float sv = ssum[L*N_GRAPHS + g];
      hv += (sv > 0.f) ? pp/sv : 0.f;
    }
    h[tid] = hv;
  }
  __syncthreads();
  const float* wr = lw + tid*128;
  float a = 0.f;
  for (int k = 0; k < 128; ++k) a += h[k]*wr[k];
  a = fmaxf(a + lb[tid], 0.f);
  t1[tid] = a;
  __syncthreads();
  int o = tid >> 7, j = tid & 127;
  float p = t1[j]*cw[o*256 + j] + t1[j+128]*cw[o*256 + j + 128];
  red[tid] = p; __syncthreads();
  for (int st = 64; st > 0; st >>= 1){
    if (j < st) red[tid] += red[tid+st];
    __syncthreads();
  }
  if (j == 0) out[g*2 + o] = red[tid] + cb[o];
}

extern "C" void kernel_launch(void* const* d_in, const int* in_sizes, int n_in,
                              void* d_out, int out_size, void* d_ws, size_t ws_size,
                              hipStream_t stream){
  const float* x   = (const float*)d_in[0];
  const int*   ei  = (const int*)d_in[1];
  const int* batch = (const int*)d_in[2];
  const float* w0  = (const float*)d_in[3];
  const float* b0  = (const float*)d_in[4];
  const float* w1  = (const float*)d_in[5];
  const float* b1  = (const float*)d_in[6];
  const float* w2  = (const float*)d_in[7];
  const float* b2  = (const float*)d_in[8];
  const float* gw  = (const float*)d_in[9];
  const float* gb  = (const float*)d_in[10];
  const float* lw  = (const float*)d_in[11];
  const float* lb  = (const float*)d_in[12];
  const float* cw  = (const float*)d_in[13];
  const float* cb  = (const float*)d_in[14];
  float* out = (float*)d_out;
  (void)in_sizes; (void)n_in; (void)out_size; (void)ws_size;

  char* ws = (char*)d_ws;
  size_t off = 0;
  auto alloc = [&](size_t bytes)->char*{
    char* p = ws + off;
    off = (off + bytes + 255) & ~(size_t)255;
    return p;
  };
  float* dis    = (float*)alloc((size_t)N_NODES*4);
  unsigned int* xw   = (unsigned int*)alloc((size_t)(N_NODES+1)*64*4); // +zero row
  unsigned int* xbuf = (unsigned int*)alloc((size_t)(N_NODES+1)*64*4); // +zero row
  unsigned int* Wb0  = (unsigned int*)alloc((size_t)DIM*64*4);
  unsigned int* Wb1  = (unsigned int*)alloc((size_t)DIM*64*4);
  unsigned int* Wb2  = (unsigned int*)alloc((size_t)DIM*64*4);
  float* gate  = (float*)alloc((size_t)N_NODES*4);
  float* hgp   = (float*)alloc((size_t)3*POOL_BLKS*DIM*4);
  float* ssum  = (float*)alloc((size_t)3*N_GRAPHS*4);
  int*   gs    = (int*)alloc((size_t)(N_GRAPHS+1)*4);
  int*   cnt   = (int*)alloc((size_t)N_NODES*4);
  int*   srcb  = (int*)alloc(((size_t)N_NODES*CAP + 64)*4);

  const int T = 256;
  zero_misc     <<<(N_NODES+128+T-1)/T, T, 0, stream>>>(cnt,
                    xw + (size_t)ZROW*64, xbuf + (size_t)ZROW*64);
  scatter_sliced<<<NCHUNK*NSLICE, T, 0, stream>>>(ei, cnt, srcb);
  prep          <<<196 + 96, T, 0, stream>>>(cnt, dis, batch, gs,
                                             w0, w1, w2, Wb0, Wb1, Wb2);

  // L0 GEMM (f32 input)
  gemm_f32<<<GEMM_BLKS, 256, 0, stream>>>(x, (const unsigned short*)Wb0, b0,
                                          dis, (unsigned short*)xw, GEMM_BLKS*4);
  // L0 aggregate
  aggregate_bf<<<AGG_BLKS, 256, 0, stream>>>((const uint4*)xw, cnt, srcb, dis,
                                             (uint4*)xbuf, gw, gb, gate);
  // pool(L0) || gemm(L1)
  pool_gemm<<<GEMM_BLKS + POOL_BLKS, 256, 0, stream>>>(
      xbuf, gate, gs, hgp, ssum,
      (const unsigned short*)Wb1, b1, dis, (unsigned short*)xw);
  // L1 aggregate
  aggregate_bf<<<AGG_BLKS, 256, 0, stream>>>((const uint4*)xw, cnt, srcb, dis,
                                             (uint4*)xbuf, gw, gb, gate);
  // pool(L1) || gemm(L2)
  pool_gemm<<<GEMM_BLKS + POOL_BLKS, 256, 0, stream>>>(
      xbuf, gate, gs, hgp + (size_t)POOL_BLKS*DIM, ssum + N_GRAPHS,
      (const unsigned short*)Wb2, b2, dis, (unsigned short*)xw);
  // L2 aggregate
  aggregate_bf<<<AGG_BLKS, 256, 0, stream>>>((const uint4*)xw, cnt, srcb, dis,
                                             (uint4*)xbuf, gw, gb, gate);
  // pool(L2)
  att_pool<<<POOL_BLKS, 256, 0, stream>>>(xbuf, gate, gs,
                                          hgp + (size_t)2*POOL_BLKS*DIM,
                                          ssum + 2*N_GRAPHS);
  head<<<N_GRAPHS, 256, 0, stream>>>(hgp, ssum, lw, lb, cw, cb, out);
}